// Round 1
// baseline (600.211 us; speedup 1.0000x reference)
//
#include <hip/hip_runtime.h>
#include <math.h>

#define B_ 4
#define S_ 1024
#define E_ 512
#define H_ 8
#define DK_ 64

// C[M,N] = A[M,K] @ W[N,K]^T + bias[N];  M=4096, N=512, K=512.
// split_heads: write C as [B,H,S,DK] (f -> h*64+d) else [M,N] row-major.
__global__ __launch_bounds__(256) void gemm_nt(const float* __restrict__ A,
                                               const float* __restrict__ W,
                                               const float* __restrict__ bias,
                                               float* __restrict__ C,
                                               int split_heads) {
    __shared__ float As[64][17];
    __shared__ float Ws[64][17];
    const int t = threadIdx.x;
    const int m0 = blockIdx.y * 64;
    const int n0 = blockIdx.x * 64;
    const int tm = t >> 4, tn = t & 15;
    const int lrow = t >> 2;           // 0..63
    const int lcol = (t & 3) * 4;      // 0,4,8,12
    float acc[4][4] = {};
    for (int kt = 0; kt < 512; kt += 16) {
        float4 av = *(const float4*)(A + (size_t)(m0 + lrow) * 512 + kt + lcol);
        As[lrow][lcol + 0] = av.x; As[lrow][lcol + 1] = av.y;
        As[lrow][lcol + 2] = av.z; As[lrow][lcol + 3] = av.w;
        float4 wv = *(const float4*)(W + (size_t)(n0 + lrow) * 512 + kt + lcol);
        Ws[lrow][lcol + 0] = wv.x; Ws[lrow][lcol + 1] = wv.y;
        Ws[lrow][lcol + 2] = wv.z; Ws[lrow][lcol + 3] = wv.w;
        __syncthreads();
#pragma unroll
        for (int kk = 0; kk < 16; ++kk) {
            float a[4], w[4];
#pragma unroll
            for (int i = 0; i < 4; ++i) a[i] = As[tm * 4 + i][kk];
#pragma unroll
            for (int j = 0; j < 4; ++j) w[j] = Ws[tn * 4 + j][kk];
#pragma unroll
            for (int i = 0; i < 4; ++i)
#pragma unroll
                for (int j = 0; j < 4; ++j)
                    acc[i][j] += a[i] * w[j];
        }
        __syncthreads();
    }
#pragma unroll
    for (int i = 0; i < 4; ++i) {
        const int m = m0 + tm * 4 + i;
        const int b = m >> 10, s = m & 1023;
#pragma unroll
        for (int j = 0; j < 4; ++j) {
            const int f = n0 + tn * 4 + j;
            const float v = acc[i][j] + bias[f];
            size_t idx;
            if (split_heads) {
                const int h = f >> 6, d = f & 63;
                idx = ((size_t)((b * H_ + h) * S_ + s)) * DK_ + d;
            } else {
                idx = (size_t)m * E_ + f;
            }
            C[idx] = v;
        }
    }
}

// Flash-style attention, fused dist-conv bias + mask + online softmax.
// grid: (S/64, B*H). Q,K,V in [B,H,S,DK]; X out in [B,S,H,DK] (== [B,S,E]).
__global__ __launch_bounds__(256) void attn_kernel(
    const float* __restrict__ Q, const float* __restrict__ K,
    const float* __restrict__ V, const float* __restrict__ dist,
    const int* __restrict__ mask,
    const float* __restrict__ cw1, const float* __restrict__ cb1,
    const float* __restrict__ cw2, const float* __restrict__ cb2,
    float* __restrict__ X) {
    __shared__ float Qs[64][65];
    __shared__ float Ks[64][65];
    __shared__ float Vs[64][65];
    __shared__ float Ss[64][65];
    __shared__ float m_s[64], l_s[64], alpha_s[64];

    const int t = threadIdx.x;
    const int bh = blockIdx.y;
    const int b = bh >> 3, h = bh & 7;
    const int q0 = blockIdx.x * 64;

    float w1[8], b1[8], w2[8];
#pragma unroll
    for (int i = 0; i < 8; ++i) {
        w1[i] = cw1[i]; b1[i] = cb1[i]; w2[i] = cw2[h * 8 + i];
    }
    const float b2 = cb2[h];

    const size_t qkv_base = (size_t)bh * S_ * DK_;
    {
        const int r = t >> 2, c0 = (t & 3) * 16;
        const float* qp = Q + qkv_base + (size_t)(q0 + r) * DK_ + c0;
#pragma unroll
        for (int j = 0; j < 16; j += 4) {
            float4 v4 = *(const float4*)(qp + j);
            Qs[r][c0 + j] = v4.x; Qs[r][c0 + j + 1] = v4.y;
            Qs[r][c0 + j + 2] = v4.z; Qs[r][c0 + j + 3] = v4.w;
        }
    }
    if (t < 64) { m_s[t] = -1e30f; l_s[t] = 0.f; }

    const int tq = t >> 4, tn = t & 15;
    float o[4][4] = {};

    for (int kt = 0; kt < S_; kt += 64) {
        __syncthreads();  // protect Ks/Vs/Ss from previous iteration's readers
        {
            const int r = t >> 2, c0 = (t & 3) * 16;
            const float* kp = K + qkv_base + (size_t)(kt + r) * DK_ + c0;
            const float* vp = V + qkv_base + (size_t)(kt + r) * DK_ + c0;
#pragma unroll
            for (int j = 0; j < 16; j += 4) {
                float4 kv = *(const float4*)(kp + j);
                Ks[r][c0 + j] = kv.x; Ks[r][c0 + j + 1] = kv.y;
                Ks[r][c0 + j + 2] = kv.z; Ks[r][c0 + j + 3] = kv.w;
                float4 vv = *(const float4*)(vp + j);
                Vs[r][c0 + j] = vv.x; Vs[r][c0 + j + 1] = vv.y;
                Vs[r][c0 + j + 2] = vv.z; Vs[r][c0 + j + 3] = vv.w;
            }
        }
        __syncthreads();

        // QK^T 4x4 micro-tile
        float sc[4][4] = {};
        for (int d = 0; d < 64; ++d) {
            float a[4], kk4[4];
#pragma unroll
            for (int i = 0; i < 4; ++i) a[i] = Qs[tq * 4 + i][d];
#pragma unroll
            for (int j = 0; j < 4; ++j) kk4[j] = Ks[tn * 4 + j][d];
#pragma unroll
            for (int i = 0; i < 4; ++i)
#pragma unroll
                for (int j = 0; j < 4; ++j)
                    sc[i][j] += a[i] * kk4[j];
        }

        // scale * conv-bias, mask, stage scores to LDS
#pragma unroll
        for (int i = 0; i < 4; ++i) {
            const int qg = q0 + tq * 4 + i;
            const int kg = kt + tn * 4;
            const size_t dbase = ((size_t)b * S_ + qg) * S_ + kg;
            float4 d4 = *(const float4*)(dist + dbase);
            int4 m4 = *(const int4*)(mask + dbase);
            float dv[4] = {d4.x, d4.y, d4.z, d4.w};
            int mv[4] = {m4.x, m4.y, m4.z, m4.w};
#pragma unroll
            for (int j = 0; j < 4; ++j) {
                float bias_v = b2;
#pragma unroll
                for (int hh = 0; hh < 8; ++hh) {
                    float tv = dv[j] * w1[hh] + b1[hh];
                    tv = tv > 0.f ? tv : 0.f;
                    bias_v += tv * w2[hh];
                }
                float sval = sc[i][j] * 0.125f * bias_v;
                if (mv[j] == 0) sval = -1e9f;
                Ss[tq * 4 + i][tn * 4 + j] = sval;
            }
        }
        __syncthreads();

        // online softmax row update (one thread per query row)
        if (t < 64) {
            float mx = -1e30f;
#pragma unroll 8
            for (int j = 0; j < 64; ++j) mx = fmaxf(mx, Ss[t][j]);
            const float mold = m_s[t];
            const float mnew = fmaxf(mold, mx);
            const float alpha = __expf(mold - mnew);
            float rs = 0.f;
#pragma unroll 8
            for (int j = 0; j < 64; ++j) {
                float p = __expf(Ss[t][j] - mnew);
                Ss[t][j] = p;
                rs += p;
            }
            l_s[t] = l_s[t] * alpha + rs;
            m_s[t] = mnew;
            alpha_s[t] = alpha;
        }
        __syncthreads();

        // rescale O, accumulate P @ V (4x4 micro-tile)
#pragma unroll
        for (int i = 0; i < 4; ++i) {
            const float al = alpha_s[tq * 4 + i];
#pragma unroll
            for (int j = 0; j < 4; ++j) o[i][j] *= al;
        }
        for (int kj = 0; kj < 64; ++kj) {
            float p[4], vv[4];
#pragma unroll
            for (int i = 0; i < 4; ++i) p[i] = Ss[tq * 4 + i][kj];
#pragma unroll
            for (int j = 0; j < 4; ++j) vv[j] = Vs[kj][tn * 4 + j];
#pragma unroll
            for (int i = 0; i < 4; ++i)
#pragma unroll
                for (int j = 0; j < 4; ++j)
                    o[i][j] += p[i] * vv[j];
        }
    }

#pragma unroll
    for (int i = 0; i < 4; ++i) {
        const int qg = q0 + tq * 4 + i;
        const float inv_l = 1.f / l_s[tq * 4 + i];
#pragma unroll
        for (int j = 0; j < 4; ++j) {
            const int d = tn * 4 + j;
            X[(((size_t)b * S_ + qg) * H_ + h) * DK_ + d] = o[i][j] * inv_l;
        }
    }
}

extern "C" void kernel_launch(void* const* d_in, const int* in_sizes, int n_in,
                              void* d_out, int out_size, void* d_ws, size_t ws_size,
                              hipStream_t stream) {
    (void)in_sizes; (void)n_in; (void)out_size; (void)ws_size;
    const float* query = (const float*)d_in[0];
    const float* key   = (const float*)d_in[1];
    const float* value = (const float*)d_in[2];
    const float* dist  = (const float*)d_in[3];
    const int*   mask  = (const int*)d_in[4];
    const float* Wq = (const float*)d_in[5];
    const float* bq = (const float*)d_in[6];
    const float* Wk = (const float*)d_in[7];
    const float* bk = (const float*)d_in[8];
    const float* Wv = (const float*)d_in[9];
    const float* bv = (const float*)d_in[10];
    const float* Wo = (const float*)d_in[11];
    const float* bo = (const float*)d_in[12];
    const float* cw1 = (const float*)d_in[13];
    const float* cb1 = (const float*)d_in[14];
    const float* cw2 = (const float*)d_in[15];
    const float* cb2 = (const float*)d_in[16];
    float* out = (float*)d_out;

    float* ws = (float*)d_ws;
    float* q_ws = ws;
    float* k_ws = ws + (size_t)2097152;
    float* v_ws = ws + (size_t)2 * 2097152;
    float* x_ws = ws + (size_t)3 * 2097152;

    dim3 gblk(256);
    dim3 ggrid(8, 64);
    hipLaunchKernelGGL(gemm_nt, ggrid, gblk, 0, stream, query, Wq, bq, q_ws, 1);
    hipLaunchKernelGGL(gemm_nt, ggrid, gblk, 0, stream, key,   Wk, bk, k_ws, 1);
    hipLaunchKernelGGL(gemm_nt, ggrid, gblk, 0, stream, value, Wv, bv, v_ws, 1);
    dim3 agrid(16, 32);
    hipLaunchKernelGGL(attn_kernel, agrid, gblk, 0, stream,
                       q_ws, k_ws, v_ws, dist, mask, cw1, cb1, cw2, cb2, x_ws);
    hipLaunchKernelGGL(gemm_nt, ggrid, gblk, 0, stream, x_ws, Wo, bo, out, 0);
}

// Round 2
// 219.570 us; speedup vs baseline: 2.7336x; 2.7336x over previous
//
#include <hip/hip_runtime.h>
#include <hip/hip_bf16.h>
#include <math.h>

#define B_ 4
#define S_ 1024
#define E_ 512
#define H_ 8
#define DK_ 64

typedef short bf16x8 __attribute__((ext_vector_type(8)));
typedef float f32x4 __attribute__((ext_vector_type(4)));

#define MFMA16(a, b, c) __builtin_amdgcn_mfma_f32_16x16x32_bf16((a), (b), (c), 0, 0, 0)

// async global->LDS, 16B per lane. LDS dest must be wave-uniform base;
// lane i lands at base + i*16.
__device__ __forceinline__ void gl_lds16(const void* gptr, void* lptr) {
    __builtin_amdgcn_global_load_lds(
        (const __attribute__((address_space(1))) unsigned int*)gptr,
        (__attribute__((address_space(3))) unsigned int*)lptr,
        16, 0, 0);
}

// ---------------------------------------------------------------------------
// fp32 -> bf16 convert for q/k/v inputs and the 4 weight matrices.
// grid: (1024, 7). z: 0..2 big tensors (2M), 3..6 weights (256K).
// ---------------------------------------------------------------------------
__global__ __launch_bounds__(256) void convert_bf16(
    const float* __restrict__ q, const float* __restrict__ k, const float* __restrict__ v,
    const float* __restrict__ wq, const float* __restrict__ wk,
    const float* __restrict__ wv, const float* __restrict__ wo,
    __hip_bfloat16* qc, __hip_bfloat16* kc, __hip_bfloat16* vc,
    __hip_bfloat16* wqc, __hip_bfloat16* wkc, __hip_bfloat16* wvc, __hip_bfloat16* woc) {
    const int z = blockIdx.y;
    const float* src;
    __hip_bfloat16* dst;
    int n;
    switch (z) {
        case 0: src = q;  dst = qc;  n = B_ * S_ * E_; break;
        case 1: src = k;  dst = kc;  n = B_ * S_ * E_; break;
        case 2: src = v;  dst = vc;  n = B_ * S_ * E_; break;
        case 3: src = wq; dst = wqc; n = E_ * E_; break;
        case 4: src = wk; dst = wkc; n = E_ * E_; break;
        case 5: src = wv; dst = wvc; n = E_ * E_; break;
        default: src = wo; dst = woc; n = E_ * E_; break;
    }
    const int idx = (blockIdx.x * 256 + threadIdx.x) * 8;
    if (idx >= n) return;
    float4 a = *(const float4*)(src + idx);
    float4 bb = *(const float4*)(src + idx + 4);
    union { __hip_bfloat16 h[8]; uint4 u; } o;
    o.h[0] = __float2bfloat16(a.x);  o.h[1] = __float2bfloat16(a.y);
    o.h[2] = __float2bfloat16(a.z);  o.h[3] = __float2bfloat16(a.w);
    o.h[4] = __float2bfloat16(bb.x); o.h[5] = __float2bfloat16(bb.y);
    o.h[6] = __float2bfloat16(bb.z); o.h[7] = __float2bfloat16(bb.w);
    *(uint4*)(dst + idx) = o.u;
}

// ---------------------------------------------------------------------------
// Shared MFMA GEMM core: C[128x64] tile of A[M,512] @ W[N,512]^T.
// A,W bf16, rows K-contiguous (1024 B). XOR-swizzled LDS (chunk c of row r
// stored at c^(r&7)) so 16B frag reads spread across all 32 banks.
// 256 thr = 4 waves in 2x2; wave computes 64x32 via 4x2 16x16 tiles.
// ---------------------------------------------------------------------------
__device__ __forceinline__ void gemm_core(const __hip_bfloat16* A, const __hip_bfloat16* W,
                                          char* sA, char* sW, int m0, int n0,
                                          f32x4 acc[4][2]) {
    const int t = threadIdx.x;
    const int w = t >> 6, lane = t & 63;
    const int wm = (w >> 1) * 64, wn = (w & 1) * 32;
    const int g = lane >> 4, ln = lane & 15;

    for (int kc = 0; kc < 8; ++kc) {
        __syncthreads();
        // A tile: 128 rows x 128B = 16 KB -> 4 calls/thread
#pragma unroll
        for (int i = 0; i < 4; ++i) {
            int L = (i * 4 + w) * 64 + lane;
            int r = L >> 3, cs = L & 7;
            int c = cs ^ (r & 7);
            gl_lds16((const char*)A + (size_t)(m0 + r) * 1024 + kc * 128 + c * 16,
                     sA + (i * 4 + w) * 1024);
        }
        // W tile: 64 rows x 128B = 8 KB -> 2 calls/thread
#pragma unroll
        for (int i = 0; i < 2; ++i) {
            int L = (i * 4 + w) * 64 + lane;
            int r = L >> 3, cs = L & 7;
            int c = cs ^ (r & 7);
            gl_lds16((const char*)W + (size_t)(n0 + r) * 1024 + kc * 128 + c * 16,
                     sW + (i * 4 + w) * 1024);
        }
        __syncthreads();
#pragma unroll
        for (int ks = 0; ks < 2; ++ks) {
            bf16x8 af[4], bf[2];
#pragma unroll
            for (int mt = 0; mt < 4; ++mt) {
                int m = wm + mt * 16 + ln;
                int c = ks * 4 + g;
                af[mt] = *(const bf16x8*)(sA + m * 128 + (c ^ (m & 7)) * 16);
            }
#pragma unroll
            for (int nt = 0; nt < 2; ++nt) {
                int n = wn + nt * 16 + ln;
                int c = ks * 4 + g;
                bf[nt] = *(const bf16x8*)(sW + n * 128 + (c ^ (n & 7)) * 16);
            }
#pragma unroll
            for (int mt = 0; mt < 4; ++mt)
#pragma unroll
                for (int nt = 0; nt < 2; ++nt)
                    acc[mt][nt] = MFMA16(af[mt], bf[nt], acc[mt][nt]);
        }
    }
}

// Batched projection GEMM. grid (8, 32, 3). z: 0=q (split-head store),
// 1=k (split-head), 2=v (transposed store [B,H,DK,S]).
__global__ __launch_bounds__(256) void proj_gemm(
    const __hip_bfloat16* __restrict__ qc, const __hip_bfloat16* __restrict__ kc,
    const __hip_bfloat16* __restrict__ vc,
    const __hip_bfloat16* __restrict__ wqc, const __hip_bfloat16* __restrict__ wkc,
    const __hip_bfloat16* __restrict__ wvc,
    const float* __restrict__ bq, const float* __restrict__ bk, const float* __restrict__ bv,
    __hip_bfloat16* qbh, __hip_bfloat16* kbh, __hip_bfloat16* vt) {
    __shared__ char sA[16384];
    __shared__ char sW[8192];
    const int z = blockIdx.z;
    const __hip_bfloat16* A;
    const __hip_bfloat16* W;
    const float* bias;
    __hip_bfloat16* dst;
    if (z == 0)      { A = qc; W = wqc; bias = bq; dst = qbh; }
    else if (z == 1) { A = kc; W = wkc; bias = bk; dst = kbh; }
    else             { A = vc; W = wvc; bias = bv; dst = vt; }

    const int m0 = blockIdx.y * 128, n0 = blockIdx.x * 64;
    f32x4 acc[4][2] = {};
    gemm_core(A, W, sA, sW, m0, n0, acc);

    const int t = threadIdx.x;
    const int w = t >> 6, lane = t & 63;
    const int wm = (w >> 1) * 64, wn = (w & 1) * 32;
    const int g = lane >> 4, ln = lane & 15;
    float bv2[2];
#pragma unroll
    for (int nt = 0; nt < 2; ++nt) bv2[nt] = bias[n0 + wn + nt * 16 + ln];
#pragma unroll
    for (int mt = 0; mt < 4; ++mt)
#pragma unroll
        for (int nt = 0; nt < 2; ++nt)
#pragma unroll
            for (int r = 0; r < 4; ++r) {
                int m = m0 + wm + mt * 16 + g * 4 + r;
                int f = n0 + wn + nt * 16 + ln;
                float val = acc[mt][nt][r] + bv2[nt];
                int b = m >> 10, s = m & 1023;
                int hh = f >> 6, d = f & 63;
                if (z == 2)
                    dst[((size_t)(b * 8 + hh) * 64 + d) * 1024 + s] = __float2bfloat16(val);
                else
                    dst[((size_t)(b * 8 + hh) * 1024 + s) * 64 + d] = __float2bfloat16(val);
            }
}

// Output GEMM: out[4096,512] fp32 = x_bf16 @ Wo^T + bo. grid (8, 32).
__global__ __launch_bounds__(256) void out_gemm(
    const __hip_bfloat16* __restrict__ X, const __hip_bfloat16* __restrict__ woc,
    const float* __restrict__ bo, float* __restrict__ out) {
    __shared__ char sA[16384];
    __shared__ char sW[8192];
    const int m0 = blockIdx.y * 128, n0 = blockIdx.x * 64;
    f32x4 acc[4][2] = {};
    gemm_core(X, woc, sA, sW, m0, n0, acc);

    const int t = threadIdx.x;
    const int w = t >> 6, lane = t & 63;
    const int wm = (w >> 1) * 64, wn = (w & 1) * 32;
    const int g = lane >> 4, ln = lane & 15;
    float bv2[2];
#pragma unroll
    for (int nt = 0; nt < 2; ++nt) bv2[nt] = bo[n0 + wn + nt * 16 + ln];
#pragma unroll
    for (int mt = 0; mt < 4; ++mt)
#pragma unroll
        for (int nt = 0; nt < 2; ++nt)
#pragma unroll
            for (int r = 0; r < 4; ++r) {
                int m = m0 + wm + mt * 16 + g * 4 + r;
                int f = n0 + wn + nt * 16 + ln;
                out[(size_t)m * 512 + f] = acc[mt][nt][r] + bv2[nt];
            }
}

// ---------------------------------------------------------------------------
// MFMA flash attention. grid (16, 32) = (qtile, b*h). 256 thr = 4 waves,
// wave w owns 16 queries. Q frags in regs; K/Vt staged via swizzled
// global_load_lds; softmax in-register (shfl width 16); P -> per-wave LDS
// region as bf16 A-operand for PV.
// ---------------------------------------------------------------------------
__global__ __launch_bounds__(256) void attn(
    const __hip_bfloat16* __restrict__ Qb, const __hip_bfloat16* __restrict__ Kb,
    const __hip_bfloat16* __restrict__ Vt,
    const float* __restrict__ dist, const int* __restrict__ mask,
    const float* __restrict__ cw1, const float* __restrict__ cb1,
    const float* __restrict__ cw2, const float* __restrict__ cb2,
    __hip_bfloat16* __restrict__ X) {
    __shared__ char sK[8192];
    __shared__ char sV[8192];
    __shared__ __hip_bfloat16 Ps[4][16][72];  // per-wave P tile, 144B rows (16B-aligned, conflict-free)

    const int t = threadIdx.x, w = t >> 6, lane = t & 63;
    const int g = lane >> 4, ln = lane & 15;
    const int bh = blockIdx.y, b = bh >> 3, h = bh & 7;
    const int q0 = blockIdx.x * 64;

    float w1[8], b1[8], w2[8];
#pragma unroll
    for (int i = 0; i < 8; ++i) {
        w1[i] = cw1[i]; b1[i] = cb1[i]; w2[i] = cw2[h * 8 + i];
    }
    const float b2v = cb2[h];

    // Q fragments (A operand), straight from global: lane ln -> query row.
    bf16x8 qf[2];
    {
        const char* qbase = (const char*)Qb + ((size_t)bh * 1024 + q0 + w * 16 + ln) * 128;
        qf[0] = *(const bf16x8*)(qbase + g * 16);
        qf[1] = *(const bf16x8*)(qbase + 64 + g * 16);
    }

    float mrow[4], lrow[4];
#pragma unroll
    for (int r = 0; r < 4; ++r) { mrow[r] = -1e30f; lrow[r] = 0.f; }
    f32x4 O[4] = {};

    const size_t kbase = (size_t)bh * 1024 * 128;  // K rows: 128 B each
    const size_t vbase = (size_t)bh * 64 * 2048;   // Vt rows: 2048 B each

    for (int kt = 0; kt < S_; kt += 64) {
        __syncthreads();
        // stage K tile (64 keys x 128B) and Vt tile (64 dk x 128B window)
#pragma unroll
        for (int i = 0; i < 2; ++i) {
            int L = (i * 4 + w) * 64 + lane;
            int r = L >> 3, cs = L & 7;
            int c = cs ^ (r & 7);
            gl_lds16((const char*)Kb + kbase + (size_t)(kt + r) * 128 + c * 16,
                     sK + (i * 4 + w) * 1024);
            gl_lds16((const char*)Vt + vbase + (size_t)r * 2048 + (size_t)kt * 2 + c * 16,
                     sV + (i * 4 + w) * 1024);
        }
        // dist/mask straight to registers (C-layout positions)
        float dv[4][4];
        int mv[4][4];
#pragma unroll
        for (int tt = 0; tt < 4; ++tt)
#pragma unroll
            for (int r = 0; r < 4; ++r) {
                size_t off = ((size_t)b * 1024 + q0 + w * 16 + g * 4 + r) * 1024 + kt + tt * 16 + ln;
                dv[tt][r] = dist[off];
                mv[tt][r] = mask[off];
            }
        __syncthreads();

        // QK^T: 4 key-tiles x 2 k-steps
        f32x4 sc[4] = {};
#pragma unroll
        for (int tt = 0; tt < 4; ++tt)
#pragma unroll
            for (int ks = 0; ks < 2; ++ks) {
                int key = tt * 16 + ln;
                int c = ks * 4 + g;
                bf16x8 kf = *(const bf16x8*)(sK + key * 128 + (c ^ (key & 7)) * 16);
                sc[tt] = MFMA16(qf[ks], kf, sc[tt]);
            }

        // scale * conv-bias, mask
        float p[4][4];
#pragma unroll
        for (int tt = 0; tt < 4; ++tt)
#pragma unroll
            for (int r = 0; r < 4; ++r) {
                float bias_v = b2v;
#pragma unroll
                for (int hh = 0; hh < 8; ++hh) {
                    float tv = dv[tt][r] * w1[hh] + b1[hh];
                    tv = fmaxf(tv, 0.f);
                    bias_v += tv * w2[hh];
                }
                float sval = sc[tt][r] * 0.125f * bias_v;
                if (mv[tt][r] == 0) sval = -1e9f;
                p[tt][r] = sval;
            }

        // online softmax: row = g*4+r, cols spread over 16 lanes of group g
        float mx[4], al[4], rs[4];
#pragma unroll
        for (int r = 0; r < 4; ++r) {
            float m4 = fmaxf(fmaxf(p[0][r], p[1][r]), fmaxf(p[2][r], p[3][r]));
#pragma unroll
            for (int sh = 1; sh < 16; sh <<= 1) m4 = fmaxf(m4, __shfl_xor(m4, sh, 16));
            mx[r] = m4;
            float mn = fmaxf(mrow[r], m4);
            al[r] = __expf(mrow[r] - mn);
            mrow[r] = mn;
        }
#pragma unroll
        for (int r = 0; r < 4; ++r) rs[r] = 0.f;
#pragma unroll
        for (int tt = 0; tt < 4; ++tt)
#pragma unroll
            for (int r = 0; r < 4; ++r) {
                float pe = __expf(p[tt][r] - mrow[r]);
                p[tt][r] = pe;
                rs[r] += pe;
            }
#pragma unroll
        for (int r = 0; r < 4; ++r) {
            float s4 = rs[r];
#pragma unroll
            for (int sh = 1; sh < 16; sh <<= 1) s4 += __shfl_xor(s4, sh, 16);
            lrow[r] = lrow[r] * al[r] + s4;
        }
        // rescale O
#pragma unroll
        for (int tt = 0; tt < 4; ++tt)
#pragma unroll
            for (int r = 0; r < 4; ++r) O[tt][r] *= al[r];

        // P -> per-wave LDS (C-layout write, A-layout read; same wave so no barrier)
#pragma unroll
        for (int tt = 0; tt < 4; ++tt)
#pragma unroll
            for (int r = 0; r < 4; ++r)
                Ps[w][g * 4 + r][tt * 16 + ln] = __float2bfloat16(p[tt][r]);

        // PV: O[16q x 64dk] += P[16q x 64key] @ V[64key x 64dk]
#pragma unroll
        for (int ks = 0; ks < 2; ++ks) {
            bf16x8 pf = *(const bf16x8*)((const char*)&Ps[w][0][0] + ln * 144 + ks * 64 + g * 16);
#pragma unroll
            for (int tt = 0; tt < 4; ++tt) {
                int dk = tt * 16 + ln;
                int c = ks * 4 + g;
                bf16x8 vf = *(const bf16x8*)(sV + dk * 128 + (c ^ (dk & 7)) * 16);
                O[tt] = MFMA16(pf, vf, O[tt]);
            }
        }
    }

    // epilogue: normalize, store bf16 x in [B,S,E] (E = h*64+dk)
#pragma unroll
    for (int r = 0; r < 4; ++r) {
        float inv = 1.f / lrow[r];
        int q = q0 + w * 16 + g * 4 + r;
#pragma unroll
        for (int tt = 0; tt < 4; ++tt) {
            int dk = tt * 16 + ln;
            X[((size_t)(b * 1024 + q)) * 512 + h * 64 + dk] = __float2bfloat16(O[tt][r] * inv);
        }
    }
}

extern "C" void kernel_launch(void* const* d_in, const int* in_sizes, int n_in,
                              void* d_out, int out_size, void* d_ws, size_t ws_size,
                              hipStream_t stream) {
    (void)in_sizes; (void)n_in; (void)out_size; (void)ws_size;
    const float* query = (const float*)d_in[0];
    const float* key   = (const float*)d_in[1];
    const float* value = (const float*)d_in[2];
    const float* dist  = (const float*)d_in[3];
    const int*   mask  = (const int*)d_in[4];
    const float* Wq = (const float*)d_in[5];
    const float* bq = (const float*)d_in[6];
    const float* Wk = (const float*)d_in[7];
    const float* bk = (const float*)d_in[8];
    const float* Wv = (const float*)d_in[9];
    const float* bv = (const float*)d_in[10];
    const float* Wo = (const float*)d_in[11];
    const float* bo = (const float*)d_in[12];
    const float* cw1 = (const float*)d_in[13];
    const float* cb1 = (const float*)d_in[14];
    const float* cw2 = (const float*)d_in[15];
    const float* cb2 = (const float*)d_in[16];
    float* out = (float*)d_out;

    char* ws = (char*)d_ws;
    const size_t MB = 1 << 20;
    __hip_bfloat16* qc  = (__hip_bfloat16*)(ws + 0 * MB);
    __hip_bfloat16* kc  = (__hip_bfloat16*)(ws + 4 * MB);
    __hip_bfloat16* vc  = (__hip_bfloat16*)(ws + 8 * MB);
    __hip_bfloat16* wqc = (__hip_bfloat16*)(ws + 12 * MB);
    __hip_bfloat16* wkc = (__hip_bfloat16*)(ws + 12 * MB + 512 * 1024);
    __hip_bfloat16* wvc = (__hip_bfloat16*)(ws + 13 * MB);
    __hip_bfloat16* woc = (__hip_bfloat16*)(ws + 13 * MB + 512 * 1024);
    __hip_bfloat16* qbh = (__hip_bfloat16*)(ws + 14 * MB);
    __hip_bfloat16* kbh = (__hip_bfloat16*)(ws + 18 * MB);
    __hip_bfloat16* vt  = (__hip_bfloat16*)(ws + 22 * MB);
    __hip_bfloat16* x   = (__hip_bfloat16*)(ws + 26 * MB);

    hipLaunchKernelGGL(convert_bf16, dim3(1024, 7), dim3(256), 0, stream,
                       query, key, value, Wq, Wk, Wv, Wo,
                       qc, kc, vc, wqc, wkc, wvc, woc);
    hipLaunchKernelGGL(proj_gemm, dim3(8, 32, 3), dim3(256), 0, stream,
                       qc, kc, vc, wqc, wkc, wvc, bq, bk, bv, qbh, kbh, vt);
    hipLaunchKernelGGL(attn, dim3(16, 32), dim3(256), 0, stream,
                       qbh, kbh, vt, dist, mask, cw1, cb1, cw2, cb2, x);
    hipLaunchKernelGGL(out_gemm, dim3(8, 32), dim3(256), 0, stream,
                       x, woc, bo, out);
}

// Round 3
// 204.286 us; speedup vs baseline: 2.9381x; 1.0748x over previous
//
#include <hip/hip_runtime.h>
#include <hip/hip_bf16.h>
#include <math.h>

#define B_ 4
#define S_ 1024
#define E_ 512
#define H_ 8
#define DK_ 64

typedef short bf16x8 __attribute__((ext_vector_type(8)));
typedef float f32x4 __attribute__((ext_vector_type(4)));

#define MFMA16(a, b, c) __builtin_amdgcn_mfma_f32_16x16x32_bf16((a), (b), (c), 0, 0, 0)

__device__ __forceinline__ void gl_lds16(const void* gptr, void* lptr) {
    __builtin_amdgcn_global_load_lds(
        (const __attribute__((address_space(1))) unsigned int*)gptr,
        (__attribute__((address_space(3))) unsigned int*)lptr,
        16, 0, 0);
}

// ---------------------------------------------------------------------------
// fp32 -> bf16 converts + md = mask ? dist : -1.0f. grid (2048, 8).
// ---------------------------------------------------------------------------
__global__ __launch_bounds__(256) void convert_bf16(
    const float* __restrict__ q, const float* __restrict__ k, const float* __restrict__ v,
    const float* __restrict__ wq, const float* __restrict__ wk,
    const float* __restrict__ wv, const float* __restrict__ wo,
    const float* __restrict__ dist, const int* __restrict__ mask,
    __hip_bfloat16* qc, __hip_bfloat16* kc, __hip_bfloat16* vc,
    __hip_bfloat16* wqc, __hip_bfloat16* wkc, __hip_bfloat16* wvc, __hip_bfloat16* woc,
    float* md) {
    const int z = blockIdx.y;
    const int idx = (blockIdx.x * 256 + threadIdx.x) * 8;
    if (z == 7) {
        // md pass: 4M elements
        if (idx >= B_ * S_ * S_) return;
        float4 d0 = *(const float4*)(dist + idx);
        float4 d1 = *(const float4*)(dist + idx + 4);
        int4 m0 = *(const int4*)(mask + idx);
        int4 m1 = *(const int4*)(mask + idx + 4);
        float4 o0, o1;
        o0.x = m0.x ? d0.x : -1.0f; o0.y = m0.y ? d0.y : -1.0f;
        o0.z = m0.z ? d0.z : -1.0f; o0.w = m0.w ? d0.w : -1.0f;
        o1.x = m1.x ? d1.x : -1.0f; o1.y = m1.y ? d1.y : -1.0f;
        o1.z = m1.z ? d1.z : -1.0f; o1.w = m1.w ? d1.w : -1.0f;
        *(float4*)(md + idx) = o0;
        *(float4*)(md + idx + 4) = o1;
        return;
    }
    const float* src;
    __hip_bfloat16* dst;
    int n;
    switch (z) {
        case 0: src = q;  dst = qc;  n = B_ * S_ * E_; break;
        case 1: src = k;  dst = kc;  n = B_ * S_ * E_; break;
        case 2: src = v;  dst = vc;  n = B_ * S_ * E_; break;
        case 3: src = wq; dst = wqc; n = E_ * E_; break;
        case 4: src = wk; dst = wkc; n = E_ * E_; break;
        case 5: src = wv; dst = wvc; n = E_ * E_; break;
        default: src = wo; dst = woc; n = E_ * E_; break;
    }
    if (idx >= n) return;
    float4 a = *(const float4*)(src + idx);
    float4 bb = *(const float4*)(src + idx + 4);
    union { __hip_bfloat16 h[8]; uint4 u; } o;
    o.h[0] = __float2bfloat16(a.x);  o.h[1] = __float2bfloat16(a.y);
    o.h[2] = __float2bfloat16(a.z);  o.h[3] = __float2bfloat16(a.w);
    o.h[4] = __float2bfloat16(bb.x); o.h[5] = __float2bfloat16(bb.y);
    o.h[6] = __float2bfloat16(bb.z); o.h[7] = __float2bfloat16(bb.w);
    *(uint4*)(dst + idx) = o.u;
}

// ---------------------------------------------------------------------------
// MFMA GEMM core: C[128x64] tile of A[M,512] @ W[N,512]^T (XOR-swizzled LDS).
// ---------------------------------------------------------------------------
__device__ __forceinline__ void gemm_core(const __hip_bfloat16* A, const __hip_bfloat16* W,
                                          char* sA, char* sW, int m0, int n0,
                                          f32x4 acc[4][2]) {
    const int t = threadIdx.x;
    const int w = t >> 6, lane = t & 63;
    const int wm = (w >> 1) * 64, wn = (w & 1) * 32;
    const int g = lane >> 4, ln = lane & 15;

    for (int kc = 0; kc < 8; ++kc) {
        __syncthreads();
#pragma unroll
        for (int i = 0; i < 4; ++i) {
            int L = (i * 4 + w) * 64 + lane;
            int r = L >> 3, cs = L & 7;
            int c = cs ^ (r & 7);
            gl_lds16((const char*)A + (size_t)(m0 + r) * 1024 + kc * 128 + c * 16,
                     sA + (i * 4 + w) * 1024);
        }
#pragma unroll
        for (int i = 0; i < 2; ++i) {
            int L = (i * 4 + w) * 64 + lane;
            int r = L >> 3, cs = L & 7;
            int c = cs ^ (r & 7);
            gl_lds16((const char*)W + (size_t)(n0 + r) * 1024 + kc * 128 + c * 16,
                     sW + (i * 4 + w) * 1024);
        }
        __syncthreads();
#pragma unroll
        for (int ks = 0; ks < 2; ++ks) {
            bf16x8 af[4], bf[2];
#pragma unroll
            for (int mt = 0; mt < 4; ++mt) {
                int m = wm + mt * 16 + ln;
                int c = ks * 4 + g;
                af[mt] = *(const bf16x8*)(sA + m * 128 + (c ^ (m & 7)) * 16);
            }
#pragma unroll
            for (int nt = 0; nt < 2; ++nt) {
                int n = wn + nt * 16 + ln;
                int c = ks * 4 + g;
                bf[nt] = *(const bf16x8*)(sW + n * 128 + (c ^ (n & 7)) * 16);
            }
#pragma unroll
            for (int mt = 0; mt < 4; ++mt)
#pragma unroll
                for (int nt = 0; nt < 2; ++nt)
                    acc[mt][nt] = MFMA16(af[mt], bf[nt], acc[mt][nt]);
        }
    }
}

// Projections. grid (8, 32, 3). z: 0=q, 1=k split-head [B,H,S,DK];
// 2=v transposed [B,H,DK,S]. Epilogue repacks through LDS -> coalesced stores.
__global__ __launch_bounds__(256) void proj_gemm(
    const __hip_bfloat16* __restrict__ qc, const __hip_bfloat16* __restrict__ kc,
    const __hip_bfloat16* __restrict__ vc,
    const __hip_bfloat16* __restrict__ wqc, const __hip_bfloat16* __restrict__ wkc,
    const __hip_bfloat16* __restrict__ wvc,
    const float* __restrict__ bq, const float* __restrict__ bk, const float* __restrict__ bv,
    __hip_bfloat16* qbh, __hip_bfloat16* kbh, __hip_bfloat16* vt) {
    __shared__ char smem[24576];
    char* sA = smem;
    char* sW = smem + 16384;
    const int z = blockIdx.z;
    const __hip_bfloat16* A;
    const __hip_bfloat16* W;
    const float* bias;
    __hip_bfloat16* dst;
    if (z == 0)      { A = qc; W = wqc; bias = bq; dst = qbh; }
    else if (z == 1) { A = kc; W = wkc; bias = bk; dst = kbh; }
    else             { A = vc; W = wvc; bias = bv; dst = vt; }

    const int m0 = blockIdx.y * 128, n0 = blockIdx.x * 64;
    f32x4 acc[4][2] = {};
    gemm_core(A, W, sA, sW, m0, n0, acc);
    __syncthreads();  // done with sA/sW; reuse for repack

    const int t = threadIdx.x;
    const int w = t >> 6, lane = t & 63;
    const int wm = (w >> 1) * 64, wn = (w & 1) * 32;
    const int g = lane >> 4, ln = lane & 15;
    const int b = m0 >> 10;
    const int hh = n0 >> 6;
    float bv2[2];
#pragma unroll
    for (int nt = 0; nt < 2; ++nt) bv2[nt] = bias[n0 + wn + nt * 16 + ln];

    __hip_bfloat16* T = (__hip_bfloat16*)smem;
    if (z != 2) {
        // tile rows padded to 72 bf16 (144 B, 16B-aligned for b128 reads)
#pragma unroll
        for (int mt = 0; mt < 4; ++mt)
#pragma unroll
            for (int nt = 0; nt < 2; ++nt)
#pragma unroll
                for (int r = 0; r < 4; ++r) {
                    int lm = wm + mt * 16 + g * 4 + r;
                    int n = wn + nt * 16 + ln;
                    T[lm * 72 + n] = __float2bfloat16(acc[mt][nt][r] + bv2[nt]);
                }
        __syncthreads();
        // row-major readback: thread = half-row (64 B), coalesced dwordx4 out
        const int lm = t >> 1, half = t & 1;
        const char* srow = smem + lm * 144 + half * 64;
        char* gdst = (char*)dst +
                     (((size_t)(b * 8 + hh) * 1024 + (m0 & 1023) + lm) * 64) * 2 + half * 64;
#pragma unroll
        for (int j = 0; j < 4; ++j)
            *(uint4*)(gdst + j * 16) = *(const uint4*)(srow + j * 16);
    } else {
        // tile rows padded to 66 bf16 (132 B, odd word stride for column reads)
#pragma unroll
        for (int mt = 0; mt < 4; ++mt)
#pragma unroll
            for (int nt = 0; nt < 2; ++nt)
#pragma unroll
                for (int r = 0; r < 4; ++r) {
                    int lm = wm + mt * 16 + g * 4 + r;
                    int n = wn + nt * 16 + ln;
                    T[lm * 66 + n] = __float2bfloat16(acc[mt][nt][r] + bv2[nt]);
                }
        __syncthreads();
        // transposed readback: thread = (dk, 32-s chunk), contiguous store
        const int dk = t >> 2, a = t & 3;
        union { __hip_bfloat16 h[32]; uint4 u[4]; } P;
#pragma unroll
        for (int i = 0; i < 32; ++i)
            P.h[i] = T[(a * 32 + i) * 66 + dk];
        char* gdst = (char*)vt +
                     (((size_t)(b * 8 + hh) * 64 + dk) * 1024 + (m0 & 1023) + a * 32) * 2;
#pragma unroll
        for (int j = 0; j < 4; ++j)
            *(uint4*)(gdst + j * 16) = P.u[j];
    }
}

// Output GEMM: out[4096,512] fp32. grid (8, 32).
__global__ __launch_bounds__(256) void out_gemm(
    const __hip_bfloat16* __restrict__ X, const __hip_bfloat16* __restrict__ woc,
    const float* __restrict__ bo, float* __restrict__ out) {
    __shared__ char smem[24576];
    char* sA = smem;
    char* sW = smem + 16384;
    const int m0 = blockIdx.y * 128, n0 = blockIdx.x * 64;
    f32x4 acc[4][2] = {};
    gemm_core(X, woc, sA, sW, m0, n0, acc);

    const int t = threadIdx.x;
    const int w = t >> 6, lane = t & 63;
    const int wm = (w >> 1) * 64, wn = (w & 1) * 32;
    const int g = lane >> 4, ln = lane & 15;
    float bv2[2];
#pragma unroll
    for (int nt = 0; nt < 2; ++nt) bv2[nt] = bo[n0 + wn + nt * 16 + ln];
#pragma unroll
    for (int mt = 0; mt < 4; ++mt)
#pragma unroll
        for (int nt = 0; nt < 2; ++nt)
#pragma unroll
            for (int r = 0; r < 4; ++r) {
                int m = m0 + wm + mt * 16 + g * 4 + r;
                int f = n0 + wn + nt * 16 + ln;
                out[(size_t)m * 512 + f] = acc[mt][nt][r] + bv2[nt];
            }
}

// ---------------------------------------------------------------------------
// MFMA flash attention with row-stage softmax. grid (16, 32).
// Scores: MFMA C-layout -> per-wave LDS -> row-layout (4 lanes x 16 k per row)
// so md loads are dwordx4-coalesced and P writes are 2x b128.
// ---------------------------------------------------------------------------
__global__ __launch_bounds__(256) void attn(
    const __hip_bfloat16* __restrict__ Qb, const __hip_bfloat16* __restrict__ Kb,
    const __hip_bfloat16* __restrict__ Vt, const float* __restrict__ md,
    const float* __restrict__ cw1, const float* __restrict__ cb1,
    const float* __restrict__ cw2, const float* __restrict__ cb2,
    __hip_bfloat16* __restrict__ X) {
    __shared__ char sK[8192];
    __shared__ char sV[8192];
    __shared__ float sSc[4][16][66];          // per-wave raw scores (264 B rows)
    __shared__ __hip_bfloat16 sP[4][16][72];  // per-wave P tile (144 B rows)
    __shared__ float sBr[4][16];              // per-wave alpha / l broadcast

    const int t = threadIdx.x, w = t >> 6, lane = t & 63;
    const int g = lane >> 4, ln = lane & 15;
    const int qr = lane >> 2, a = lane & 3;   // row-stage mapping
    const int bh = blockIdx.y, b = bh >> 3, h = bh & 7;
    const int q0 = blockIdx.x * 64;

    float w1[8], b1[8], w2[8];
#pragma unroll
    for (int i = 0; i < 8; ++i) {
        w1[i] = cw1[i]; b1[i] = cb1[i]; w2[i] = cw2[h * 8 + i];
    }
    const float b2v = cb2[h];

    // Q fragments (A operand) straight from global
    bf16x8 qf[2];
    {
        const char* qbase = (const char*)Qb + ((size_t)bh * 1024 + q0 + w * 16 + ln) * 128;
        qf[0] = *(const bf16x8*)(qbase + g * 16);
        qf[1] = *(const bf16x8*)(qbase + 64 + g * 16);
    }

    float m_st = -1e30f, l_st = 0.f;  // state for row qr (replicated in 4 lanes)
    f32x4 O[4] = {};

    const size_t kbase = (size_t)bh * 1024 * 128;
    const size_t vbase = (size_t)bh * 64 * 2048;
    const float* mdrow = md + ((size_t)b * 1024 + q0 + w * 16 + qr) * 1024;

    for (int kt = 0; kt < S_; kt += 64) {
        __syncthreads();
#pragma unroll
        for (int i = 0; i < 2; ++i) {
            int L = (i * 4 + w) * 64 + lane;
            int r = L >> 3, cs = L & 7;
            int c = cs ^ (r & 7);
            gl_lds16((const char*)Kb + kbase + (size_t)(kt + r) * 128 + c * 16,
                     sK + (i * 4 + w) * 1024);
            gl_lds16((const char*)Vt + vbase + (size_t)r * 2048 + (size_t)kt * 2 + c * 16,
                     sV + (i * 4 + w) * 1024);
        }
        // md loads for row-stage (coalesced dwordx4)
        float4 md4[4];
#pragma unroll
        for (int j = 0; j < 4; ++j)
            md4[j] = *(const float4*)(mdrow + kt + a * 16 + j * 4);
        __syncthreads();

        // QK^T (C-layout)
        f32x4 sc[4] = {};
#pragma unroll
        for (int tt = 0; tt < 4; ++tt)
#pragma unroll
            for (int ks = 0; ks < 2; ++ks) {
                int key = tt * 16 + ln;
                int c = ks * 4 + g;
                bf16x8 kf = *(const bf16x8*)(sK + key * 128 + (c ^ (key & 7)) * 16);
                sc[tt] = MFMA16(qf[ks], kf, sc[tt]);
            }

        // C-layout -> per-wave LDS
#pragma unroll
        for (int tt = 0; tt < 4; ++tt)
#pragma unroll
            for (int r = 0; r < 4; ++r)
                sSc[w][g * 4 + r][tt * 16 + ln] = sc[tt][r];

        // row-stage: read 16 contiguous scores for row qr
        float sr[16];
        {
            const float* scrow = &sSc[w][qr][a * 16];
#pragma unroll
            for (int j = 0; j < 8; ++j) {
                float2 v2 = *(const float2*)(scrow + j * 2);
                sr[j * 2] = v2.x; sr[j * 2 + 1] = v2.y;
            }
        }
        // bias + mask + track max
        float mx = -1e30f;
#pragma unroll
        for (int j = 0; j < 4; ++j) {
            float dvv[4] = {md4[j].x, md4[j].y, md4[j].z, md4[j].w};
#pragma unroll
            for (int e = 0; e < 4; ++e) {
                float d = dvv[e];
                float bias_v = b2v;
#pragma unroll
                for (int hh = 0; hh < 8; ++hh) {
                    float tv = fmaf(d, w1[hh], b1[hh]);
                    tv = fmaxf(tv, 0.f);
                    bias_v = fmaf(tv, w2[hh], bias_v);
                }
                float sval = sr[j * 4 + e] * 0.125f * bias_v;
                if (d < 0.f) sval = -1e9f;
                sr[j * 4 + e] = sval;
                mx = fmaxf(mx, sval);
            }
        }
        // row max across the 4 lanes owning this row
        mx = fmaxf(mx, __shfl_xor(mx, 1));
        mx = fmaxf(mx, __shfl_xor(mx, 2));
        const float mnew = fmaxf(m_st, mx);
        const float alpha = __expf(m_st - mnew);
        m_st = mnew;
        float rs = 0.f;
        union { __hip_bfloat16 hh16[16]; uint4 u[2]; } Pk;
#pragma unroll
        for (int i = 0; i < 16; ++i) {
            float p = __expf(sr[i] - mnew);
            rs += p;
            Pk.hh16[i] = __float2bfloat16(p);
        }
        rs += __shfl_xor(rs, 1);
        rs += __shfl_xor(rs, 2);
        l_st = l_st * alpha + rs;
        // P -> per-wave LDS (contiguous 32 B per thread)
        *(uint4*)(&sP[w][qr][a * 16]) = Pk.u[0];
        *(uint4*)(&sP[w][qr][a * 16 + 8]) = Pk.u[1];
        // alpha broadcast to C-layout lanes
        if (a == 0) sBr[w][qr] = alpha;
        float al4[4];
#pragma unroll
        for (int r = 0; r < 4; ++r) al4[r] = sBr[w][g * 4 + r];
#pragma unroll
        for (int tt = 0; tt < 4; ++tt)
#pragma unroll
            for (int r = 0; r < 4; ++r) O[tt][r] *= al4[r];

        // PV
#pragma unroll
        for (int ks = 0; ks < 2; ++ks) {
            bf16x8 pf = *(const bf16x8*)(&sP[w][ln][ks * 32 + g * 8]);
#pragma unroll
            for (int tt = 0; tt < 4; ++tt) {
                int dk = tt * 16 + ln;
                int c = ks * 4 + g;
                bf16x8 vf = *(const bf16x8*)(sV + dk * 128 + (c ^ (dk & 7)) * 16);
                O[tt] = MFMA16(pf, vf, O[tt]);
            }
        }
    }

    // final l broadcast, normalize, store
    if (a == 0) sBr[w][qr] = l_st;
    __builtin_amdgcn_s_waitcnt(0);  // lgkm drain before cross-lane read
#pragma unroll
    for (int r = 0; r < 4; ++r) {
        float inv = 1.f / sBr[w][g * 4 + r];
        int q = q0 + w * 16 + g * 4 + r;
#pragma unroll
        for (int tt = 0; tt < 4; ++tt) {
            int dk = tt * 16 + ln;
            X[((size_t)(b * 1024 + q)) * 512 + h * 64 + dk] = __float2bfloat16(O[tt][r] * inv);
        }
    }
}

extern "C" void kernel_launch(void* const* d_in, const int* in_sizes, int n_in,
                              void* d_out, int out_size, void* d_ws, size_t ws_size,
                              hipStream_t stream) {
    (void)in_sizes; (void)n_in; (void)out_size; (void)ws_size;
    const float* query = (const float*)d_in[0];
    const float* key   = (const float*)d_in[1];
    const float* value = (const float*)d_in[2];
    const float* dist  = (const float*)d_in[3];
    const int*   mask  = (const int*)d_in[4];
    const float* Wq = (const float*)d_in[5];
    const float* bq = (const float*)d_in[6];
    const float* Wk = (const float*)d_in[7];
    const float* bk = (const float*)d_in[8];
    const float* Wv = (const float*)d_in[9];
    const float* bv = (const float*)d_in[10];
    const float* Wo = (const float*)d_in[11];
    const float* bo = (const float*)d_in[12];
    const float* cw1 = (const float*)d_in[13];
    const float* cb1 = (const float*)d_in[14];
    const float* cw2 = (const float*)d_in[15];
    const float* cb2 = (const float*)d_in[16];
    float* out = (float*)d_out;

    char* ws = (char*)d_ws;
    const size_t MB = 1 << 20;
    __hip_bfloat16* qc  = (__hip_bfloat16*)(ws + 0 * MB);
    __hip_bfloat16* kc  = (__hip_bfloat16*)(ws + 4 * MB);
    __hip_bfloat16* vc  = (__hip_bfloat16*)(ws + 8 * MB);
    __hip_bfloat16* wqc = (__hip_bfloat16*)(ws + 12 * MB);
    __hip_bfloat16* wkc = (__hip_bfloat16*)(ws + 12 * MB + 512 * 1024);
    __hip_bfloat16* wvc = (__hip_bfloat16*)(ws + 13 * MB);
    __hip_bfloat16* woc = (__hip_bfloat16*)(ws + 13 * MB + 512 * 1024);
    __hip_bfloat16* qbh = (__hip_bfloat16*)(ws + 14 * MB);
    __hip_bfloat16* kbh = (__hip_bfloat16*)(ws + 18 * MB);
    __hip_bfloat16* vt  = (__hip_bfloat16*)(ws + 22 * MB);
    __hip_bfloat16* x   = (__hip_bfloat16*)(ws + 26 * MB);
    float*          mdp = (float*)(ws + 30 * MB);

    hipLaunchKernelGGL(convert_bf16, dim3(2048, 8), dim3(256), 0, stream,
                       query, key, value, Wq, Wk, Wv, Wo, dist, mask,
                       qc, kc, vc, wqc, wkc, wvc, woc, mdp);
    hipLaunchKernelGGL(proj_gemm, dim3(8, 32, 3), dim3(256), 0, stream,
                       qc, kc, vc, wqc, wkc, wvc, bq, bk, bv, qbh, kbh, vt);
    hipLaunchKernelGGL(attn, dim3(16, 32), dim3(256), 0, stream,
                       qbh, kbh, vt, mdp, cw1, cb1, cw2, cb2, x);
    hipLaunchKernelGGL(out_gemm, dim3(8, 32), dim3(256), 0, stream,
                       x, woc, bo, out);
}

// Round 4
// 200.728 us; speedup vs baseline: 2.9902x; 1.0177x over previous
//
#include <hip/hip_runtime.h>
#include <hip/hip_bf16.h>
#include <math.h>

#define B_ 4
#define S_ 1024
#define E_ 512
#define H_ 8
#define DK_ 64

typedef short bf16x8 __attribute__((ext_vector_type(8)));
typedef float f32x4 __attribute__((ext_vector_type(4)));

#define MFMA16(a, b, c) __builtin_amdgcn_mfma_f32_16x16x32_bf16((a), (b), (c), 0, 0, 0)
#define cfence() asm volatile("" ::: "memory")

__device__ __forceinline__ void gl_lds16(const void* gptr, void* lptr) {
    __builtin_amdgcn_global_load_lds(
        (const __attribute__((address_space(1))) unsigned int*)gptr,
        (__attribute__((address_space(3))) unsigned int*)lptr,
        16, 0, 0);
}

__device__ __forceinline__ unsigned short bf16_bits(float v) {
    __hip_bfloat16 h = __float2bfloat16(v);
    return *(unsigned short*)&h;
}

// ---------------------------------------------------------------------------
// fp32 -> bf16 converts, exact-size 1D grid (3584 blocks).
// ---------------------------------------------------------------------------
__global__ __launch_bounds__(256) void convert_bf16(
    const float* __restrict__ q, const float* __restrict__ k, const float* __restrict__ v,
    const float* __restrict__ wq, const float* __restrict__ wk,
    const float* __restrict__ wv, const float* __restrict__ wo,
    __hip_bfloat16* qc, __hip_bfloat16* kc, __hip_bfloat16* vc,
    __hip_bfloat16* wqc, __hip_bfloat16* wkc, __hip_bfloat16* wvc, __hip_bfloat16* woc) {
    const int blk = blockIdx.x;
    const float* src;
    __hip_bfloat16* dst;
    int base;
    if (blk < 1024)      { src = q; dst = qc; base = blk; }
    else if (blk < 2048) { src = k; dst = kc; base = blk - 1024; }
    else if (blk < 3072) { src = v; dst = vc; base = blk - 2048; }
    else {
        const int wz = (blk - 3072) >> 7;
        base = (blk - 3072) & 127;
        switch (wz) {
            case 0: src = wq; dst = wqc; break;
            case 1: src = wk; dst = wkc; break;
            case 2: src = wv; dst = wvc; break;
            default: src = wo; dst = woc; break;
        }
    }
    const int idx = (base * 256 + threadIdx.x) * 8;
    float4 a = *(const float4*)(src + idx);
    float4 bb = *(const float4*)(src + idx + 4);
    union { __hip_bfloat16 h[8]; uint4 u; } o;
    o.h[0] = __float2bfloat16(a.x);  o.h[1] = __float2bfloat16(a.y);
    o.h[2] = __float2bfloat16(a.z);  o.h[3] = __float2bfloat16(a.w);
    o.h[4] = __float2bfloat16(bb.x); o.h[5] = __float2bfloat16(bb.y);
    o.h[6] = __float2bfloat16(bb.z); o.h[7] = __float2bfloat16(bb.w);
    *(uint4*)(dst + idx) = o.u;
}

// ---------------------------------------------------------------------------
// Precompute biasS[b,g,i,j] = (conv-bias) * 0.125 as bf16; masked -> 0xFF80
// (bf16 -inf, used as in-band magic; natural |bias*0.125| <~ 10, never inf).
// grid: 4096 blocks = one (b,i) row each; thread covers 4 j.
// relu terms shared across all 8 output heads.
// ---------------------------------------------------------------------------
__global__ __launch_bounds__(256) void bias_pre(
    const float* __restrict__ dist, const int* __restrict__ mask,
    const float* __restrict__ cw1, const float* __restrict__ cb1,
    const float* __restrict__ cw2, const float* __restrict__ cb2,
    __hip_bfloat16* __restrict__ biasS) {
    const int bi = blockIdx.x;
    const int b = bi >> 10, i = bi & 1023;
    const int j0 = threadIdx.x * 4;
    const size_t dbase = ((size_t)b * 1024 + i) * 1024 + j0;
    float4 d4 = *(const float4*)(dist + dbase);
    int4 m4 = *(const int4*)(mask + dbase);
    float dv[4] = {d4.x, d4.y, d4.z, d4.w};
    int mv[4] = {m4.x, m4.y, m4.z, m4.w};
    float tt[4][8];
#pragma unroll
    for (int e = 0; e < 4; ++e)
#pragma unroll
        for (int h = 0; h < 8; ++h)
            tt[e][h] = fmaxf(fmaf(dv[e], cw1[h], cb1[h]), 0.f);
#pragma unroll
    for (int g = 0; g < 8; ++g) {
        const float c2 = cb2[g];
        union { unsigned short us[4]; uint2 u2; } o;
#pragma unroll
        for (int e = 0; e < 4; ++e) {
            float bv = c2;
#pragma unroll
            for (int h = 0; h < 8; ++h) bv = fmaf(tt[e][h], cw2[g * 8 + h], bv);
            unsigned short u = bf16_bits(bv * 0.125f);
            if (mv[e] == 0) u = 0xFF80u;
            o.us[e] = u;
        }
        *(uint2*)(biasS + ((size_t)(b * 8 + g) * 1024 + i) * 1024 + j0) = o.u2;
    }
}

// ---------------------------------------------------------------------------
// MFMA GEMM core: C[128x64] tile of A[M,512] @ W[N,512]^T (XOR-swizzled LDS).
// ---------------------------------------------------------------------------
__device__ __forceinline__ void gemm_core(const __hip_bfloat16* A, const __hip_bfloat16* W,
                                          char* sA, char* sW, int m0, int n0,
                                          f32x4 acc[4][2]) {
    const int t = threadIdx.x;
    const int w = t >> 6, lane = t & 63;
    const int wm = (w >> 1) * 64, wn = (w & 1) * 32;
    const int g = lane >> 4, ln = lane & 15;

    for (int kc = 0; kc < 8; ++kc) {
        __syncthreads();
#pragma unroll
        for (int i = 0; i < 4; ++i) {
            int L = (i * 4 + w) * 64 + lane;
            int r = L >> 3, cs = L & 7;
            int c = cs ^ (r & 7);
            gl_lds16((const char*)A + (size_t)(m0 + r) * 1024 + kc * 128 + c * 16,
                     sA + (i * 4 + w) * 1024);
        }
#pragma unroll
        for (int i = 0; i < 2; ++i) {
            int L = (i * 4 + w) * 64 + lane;
            int r = L >> 3, cs = L & 7;
            int c = cs ^ (r & 7);
            gl_lds16((const char*)W + (size_t)(n0 + r) * 1024 + kc * 128 + c * 16,
                     sW + (i * 4 + w) * 1024);
        }
        __syncthreads();
#pragma unroll
        for (int ks = 0; ks < 2; ++ks) {
            bf16x8 af[4], bf[2];
#pragma unroll
            for (int mt = 0; mt < 4; ++mt) {
                int m = wm + mt * 16 + ln;
                int c = ks * 4 + g;
                af[mt] = *(const bf16x8*)(sA + m * 128 + (c ^ (m & 7)) * 16);
            }
#pragma unroll
            for (int nt = 0; nt < 2; ++nt) {
                int n = wn + nt * 16 + ln;
                int c = ks * 4 + g;
                bf[nt] = *(const bf16x8*)(sW + n * 128 + (c ^ (n & 7)) * 16);
            }
#pragma unroll
            for (int mt = 0; mt < 4; ++mt)
#pragma unroll
                for (int nt = 0; nt < 2; ++nt)
                    acc[mt][nt] = MFMA16(af[mt], bf[nt], acc[mt][nt]);
        }
    }
}

// Projections. grid (8, 32, 3). z: 0=q, 1=k split-head [B,H,S,DK];
// 2=v transposed [B,H,DK,S]. Epilogue repacks through LDS -> coalesced stores.
__global__ __launch_bounds__(256) void proj_gemm(
    const __hip_bfloat16* __restrict__ qc, const __hip_bfloat16* __restrict__ kc,
    const __hip_bfloat16* __restrict__ vc,
    const __hip_bfloat16* __restrict__ wqc, const __hip_bfloat16* __restrict__ wkc,
    const __hip_bfloat16* __restrict__ wvc,
    const float* __restrict__ bq, const float* __restrict__ bk, const float* __restrict__ bv,
    __hip_bfloat16* qbh, __hip_bfloat16* kbh, __hip_bfloat16* vt) {
    __shared__ char smem[24576];
    char* sA = smem;
    char* sW = smem + 16384;
    const int z = blockIdx.z;
    const __hip_bfloat16* A;
    const __hip_bfloat16* W;
    const float* bias;
    __hip_bfloat16* dst;
    if (z == 0)      { A = qc; W = wqc; bias = bq; dst = qbh; }
    else if (z == 1) { A = kc; W = wkc; bias = bk; dst = kbh; }
    else             { A = vc; W = wvc; bias = bv; dst = vt; }

    const int m0 = blockIdx.y * 128, n0 = blockIdx.x * 64;
    f32x4 acc[4][2] = {};
    gemm_core(A, W, sA, sW, m0, n0, acc);
    __syncthreads();  // done with sA/sW; reuse for repack

    const int t = threadIdx.x;
    const int w = t >> 6, lane = t & 63;
    const int wm = (w >> 1) * 64, wn = (w & 1) * 32;
    const int g = lane >> 4, ln = lane & 15;
    const int b = m0 >> 10;
    const int hh = n0 >> 6;
    float bv2[2];
#pragma unroll
    for (int nt = 0; nt < 2; ++nt) bv2[nt] = bias[n0 + wn + nt * 16 + ln];

    __hip_bfloat16* T = (__hip_bfloat16*)smem;
    if (z != 2) {
#pragma unroll
        for (int mt = 0; mt < 4; ++mt)
#pragma unroll
            for (int nt = 0; nt < 2; ++nt)
#pragma unroll
                for (int r = 0; r < 4; ++r) {
                    int lm = wm + mt * 16 + g * 4 + r;
                    int n = wn + nt * 16 + ln;
                    T[lm * 72 + n] = __float2bfloat16(acc[mt][nt][r] + bv2[nt]);
                }
        __syncthreads();
        const int lm = t >> 1, half = t & 1;
        const char* srow = smem + lm * 144 + half * 64;
        char* gdst = (char*)dst +
                     (((size_t)(b * 8 + hh) * 1024 + (m0 & 1023) + lm) * 64) * 2 + half * 64;
#pragma unroll
        for (int j = 0; j < 4; ++j)
            *(uint4*)(gdst + j * 16) = *(const uint4*)(srow + j * 16);
    } else {
#pragma unroll
        for (int mt = 0; mt < 4; ++mt)
#pragma unroll
            for (int nt = 0; nt < 2; ++nt)
#pragma unroll
                for (int r = 0; r < 4; ++r) {
                    int lm = wm + mt * 16 + g * 4 + r;
                    int n = wn + nt * 16 + ln;
                    T[lm * 66 + n] = __float2bfloat16(acc[mt][nt][r] + bv2[nt]);
                }
        __syncthreads();
        const int dk = t >> 2, a = t & 3;
        union { __hip_bfloat16 h[32]; uint4 u[4]; } P;
#pragma unroll
        for (int i = 0; i < 32; ++i)
            P.h[i] = T[(a * 32 + i) * 66 + dk];
        char* gdst = (char*)vt +
                     (((size_t)(b * 8 + hh) * 64 + dk) * 1024 + (m0 & 1023) + a * 32) * 2;
#pragma unroll
        for (int j = 0; j < 4; ++j)
            *(uint4*)(gdst + j * 16) = P.u[j];
    }
}

// Output GEMM: out[4096,512] fp32. grid (8, 32).
__global__ __launch_bounds__(256) void out_gemm(
    const __hip_bfloat16* __restrict__ X, const __hip_bfloat16* __restrict__ woc,
    const float* __restrict__ bo, float* __restrict__ out) {
    __shared__ char smem[24576];
    char* sA = smem;
    char* sW = smem + 16384;
    const int m0 = blockIdx.y * 128, n0 = blockIdx.x * 64;
    f32x4 acc[4][2] = {};
    gemm_core(X, woc, sA, sW, m0, n0, acc);

    const int t = threadIdx.x;
    const int w = t >> 6, lane = t & 63;
    const int wm = (w >> 1) * 64, wn = (w & 1) * 32;
    const int g = lane >> 4, ln = lane & 15;
    float bv2[2];
#pragma unroll
    for (int nt = 0; nt < 2; ++nt) bv2[nt] = bo[n0 + wn + nt * 16 + ln];
#pragma unroll
    for (int mt = 0; mt < 4; ++mt)
#pragma unroll
        for (int nt = 0; nt < 2; ++nt)
#pragma unroll
            for (int r = 0; r < 4; ++r) {
                int m = m0 + wm + mt * 16 + g * 4 + r;
                int f = n0 + wn + nt * 16 + ln;
                out[(size_t)m * 512 + f] = acc[mt][nt][r] + bv2[nt];
            }
}

// ---------------------------------------------------------------------------
// MFMA flash attention, precomputed bias. grid (16, 32).
// Score C-layout -> per-wave LDS -> row layout; bias read directly from
// global in row layout (bf16, premultiplied, 0xFF80 = masked).
// P tile aliases the score-stage LDS (per-wave in-order DS).
// ---------------------------------------------------------------------------
__global__ __launch_bounds__(256) void attn(
    const __hip_bfloat16* __restrict__ Qb, const __hip_bfloat16* __restrict__ Kb,
    const __hip_bfloat16* __restrict__ Vt, const __hip_bfloat16* __restrict__ biasS,
    __hip_bfloat16* __restrict__ X) {
    __shared__ char sK[8192];
    __shared__ char sV[8192];
    __shared__ char sScP[4][4352];   // per-wave: f32 scores 16x66 OR bf16 P 16x72 (aliased)
    __shared__ float sBr[4][16];

    const int t = threadIdx.x, w = t >> 6, lane = t & 63;
    const int g = lane >> 4, ln = lane & 15;
    const int qr = lane >> 2, a = lane & 3;
    const int bh = blockIdx.y;
    const int q0 = blockIdx.x * 64;

    float* sc = (float*)(sScP[w]);
    __hip_bfloat16* sp = (__hip_bfloat16*)(sScP[w]);

    // Q fragments (A operand) straight from global
    bf16x8 qf[2];
    {
        const char* qbase = (const char*)Qb + ((size_t)bh * 1024 + q0 + w * 16 + ln) * 128;
        qf[0] = *(const bf16x8*)(qbase + g * 16);
        qf[1] = *(const bf16x8*)(qbase + 64 + g * 16);
    }

    float m_st = -1e30f, l_st = 0.f;
    f32x4 O[4] = {};

    const size_t kbase = (size_t)bh * 1024 * 128;
    const size_t vbase = (size_t)bh * 64 * 2048;
    const __hip_bfloat16* brow = biasS + ((size_t)bh * 1024 + q0 + w * 16 + qr) * 1024;

    for (int kt = 0; kt < S_; kt += 64) {
        __syncthreads();
#pragma unroll
        for (int i = 0; i < 2; ++i) {
            int L = (i * 4 + w) * 64 + lane;
            int r = L >> 3, cs = L & 7;
            int c = cs ^ (r & 7);
            gl_lds16((const char*)Kb + kbase + (size_t)(kt + r) * 128 + c * 16,
                     sK + (i * 4 + w) * 1024);
            gl_lds16((const char*)Vt + vbase + (size_t)r * 2048 + (size_t)kt * 2 + c * 16,
                     sV + (i * 4 + w) * 1024);
        }
        // bias row chunk: 16 bf16 per lane, coalesced 128B per 4 lanes
        union { uint4 u[2]; unsigned short us[16]; } bb;
        bb.u[0] = *(const uint4*)(brow + kt + a * 16);
        bb.u[1] = *(const uint4*)(brow + kt + a * 16 + 8);
        __syncthreads();

        // QK^T (C-layout)
        f32x4 scv[4] = {};
#pragma unroll
        for (int tt = 0; tt < 4; ++tt)
#pragma unroll
            for (int ks = 0; ks < 2; ++ks) {
                int key = tt * 16 + ln;
                int c = ks * 4 + g;
                bf16x8 kf = *(const bf16x8*)(sK + key * 128 + (c ^ (key & 7)) * 16);
                scv[tt] = MFMA16(qf[ks], kf, scv[tt]);
            }

        // C-layout -> per-wave LDS
        cfence();
#pragma unroll
        for (int tt = 0; tt < 4; ++tt)
#pragma unroll
            for (int r = 0; r < 4; ++r)
                sc[(g * 4 + r) * 66 + tt * 16 + ln] = scv[tt][r];
        cfence();

        // row-stage: 16 contiguous raw scores for row qr
        float sr[16];
        {
            const float* scrow = sc + qr * 66 + a * 16;
#pragma unroll
            for (int j = 0; j < 8; ++j) {
                float2 v2 = *(const float2*)(scrow + j * 2);
                sr[j * 2] = v2.x; sr[j * 2 + 1] = v2.y;
            }
        }
        cfence();

        // apply bias (premultiplied) + magic mask + max
        float mx = -1e30f;
#pragma unroll
        for (int e = 0; e < 16; ++e) {
            unsigned int bits = bb.us[e];
            float f = __uint_as_float(bits << 16);
            float s = sr[e] * f;
            s = (bits == 0xFF80u) ? -1e9f : s;
            sr[e] = s;
            mx = fmaxf(mx, s);
        }
        mx = fmaxf(mx, __shfl_xor(mx, 1));
        mx = fmaxf(mx, __shfl_xor(mx, 2));
        const float mnew = fmaxf(m_st, mx);
        const float alpha = __expf(m_st - mnew);
        m_st = mnew;
        float rs = 0.f;
        union { __hip_bfloat16 hh16[16]; uint4 u[2]; } Pk;
#pragma unroll
        for (int i = 0; i < 16; ++i) {
            float p = __expf(sr[i] - mnew);
            rs += p;
            Pk.hh16[i] = __float2bfloat16(p);
        }
        rs += __shfl_xor(rs, 1);
        rs += __shfl_xor(rs, 2);
        l_st = l_st * alpha + rs;

        // P -> per-wave LDS (aliased over score region; per-wave DS is in-order)
        *(uint4*)(sp + qr * 72 + a * 16) = Pk.u[0];
        *(uint4*)(sp + qr * 72 + a * 16 + 8) = Pk.u[1];
        cfence();

        if (a == 0) sBr[w][qr] = alpha;
        float al4[4];
#pragma unroll
        for (int r = 0; r < 4; ++r) al4[r] = sBr[w][g * 4 + r];
#pragma unroll
        for (int tt = 0; tt < 4; ++tt)
#pragma unroll
            for (int r = 0; r < 4; ++r) O[tt][r] *= al4[r];

        // PV
#pragma unroll
        for (int ks = 0; ks < 2; ++ks) {
            bf16x8 pf = *(const bf16x8*)(sp + ln * 72 + ks * 32 + g * 8);
#pragma unroll
            for (int tt = 0; tt < 4; ++tt) {
                int dk = tt * 16 + ln;
                int c = ks * 4 + g;
                bf16x8 vf = *(const bf16x8*)(sV + dk * 128 + (c ^ (dk & 7)) * 16);
                O[tt] = MFMA16(pf, vf, O[tt]);
            }
        }
        cfence();
    }

    if (a == 0) sBr[w][qr] = l_st;
    __builtin_amdgcn_s_waitcnt(0);
    const int b = bh >> 3, h = bh & 7;
#pragma unroll
    for (int r = 0; r < 4; ++r) {
        float inv = 1.f / sBr[w][g * 4 + r];
        int q = q0 + w * 16 + g * 4 + r;
#pragma unroll
        for (int tt = 0; tt < 4; ++tt) {
            int dk = tt * 16 + ln;
            X[((size_t)(b * 1024 + q)) * 512 + h * 64 + dk] = __float2bfloat16(O[tt][r] * inv);
        }
    }
}

extern "C" void kernel_launch(void* const* d_in, const int* in_sizes, int n_in,
                              void* d_out, int out_size, void* d_ws, size_t ws_size,
                              hipStream_t stream) {
    (void)in_sizes; (void)n_in; (void)out_size; (void)ws_size;
    const float* query = (const float*)d_in[0];
    const float* key   = (const float*)d_in[1];
    const float* value = (const float*)d_in[2];
    const float* dist  = (const float*)d_in[3];
    const int*   mask  = (const int*)d_in[4];
    const float* Wq = (const float*)d_in[5];
    const float* bq = (const float*)d_in[6];
    const float* Wk = (const float*)d_in[7];
    const float* bk = (const float*)d_in[8];
    const float* Wv = (const float*)d_in[9];
    const float* bv = (const float*)d_in[10];
    const float* Wo = (const float*)d_in[11];
    const float* bo = (const float*)d_in[12];
    const float* cw1 = (const float*)d_in[13];
    const float* cb1 = (const float*)d_in[14];
    const float* cw2 = (const float*)d_in[15];
    const float* cb2 = (const float*)d_in[16];
    float* out = (float*)d_out;

    char* ws = (char*)d_ws;
    const size_t MB = 1 << 20;
    __hip_bfloat16* qc  = (__hip_bfloat16*)(ws + 0 * MB);
    __hip_bfloat16* kc  = (__hip_bfloat16*)(ws + 4 * MB);
    __hip_bfloat16* vc  = (__hip_bfloat16*)(ws + 8 * MB);
    __hip_bfloat16* wqc = (__hip_bfloat16*)(ws + 12 * MB);
    __hip_bfloat16* wkc = (__hip_bfloat16*)(ws + 12 * MB + 512 * 1024);
    __hip_bfloat16* wvc = (__hip_bfloat16*)(ws + 13 * MB);
    __hip_bfloat16* woc = (__hip_bfloat16*)(ws + 13 * MB + 512 * 1024);
    __hip_bfloat16* qbh = (__hip_bfloat16*)(ws + 14 * MB);
    __hip_bfloat16* kbh = (__hip_bfloat16*)(ws + 18 * MB);
    __hip_bfloat16* vt  = (__hip_bfloat16*)(ws + 22 * MB);
    __hip_bfloat16* x   = (__hip_bfloat16*)(ws + 26 * MB);
    __hip_bfloat16* bS  = (__hip_bfloat16*)(ws + 32 * MB);  // 64 MB

    hipLaunchKernelGGL(convert_bf16, dim3(3584), dim3(256), 0, stream,
                       query, key, value, Wq, Wk, Wv, Wo,
                       qc, kc, vc, wqc, wkc, wvc, woc);
    hipLaunchKernelGGL(bias_pre, dim3(4096), dim3(256), 0, stream,
                       dist, mask, cw1, cb1, cw2, cb2, bS);
    hipLaunchKernelGGL(proj_gemm, dim3(8, 32, 3), dim3(256), 0, stream,
                       qc, kc, vc, wqc, wkc, wvc, bq, bk, bv, qbh, kbh, vt);
    hipLaunchKernelGGL(attn, dim3(16, 32), dim3(256), 0, stream,
                       qbh, kbh, vt, bS, x);
    hipLaunchKernelGGL(out_gemm, dim3(8, 32), dim3(256), 0, stream,
                       x, woc, bo, out);
}

// Round 5
// 197.819 us; speedup vs baseline: 3.0341x; 1.0147x over previous
//
#include <hip/hip_runtime.h>
#include <hip/hip_bf16.h>
#include <math.h>

#define B_ 4
#define S_ 1024
#define E_ 512
#define H_ 8
#define DK_ 64

typedef short bf16x8 __attribute__((ext_vector_type(8)));
typedef float f32x4 __attribute__((ext_vector_type(4)));

#define MFMA16(a, b, c) __builtin_amdgcn_mfma_f32_16x16x32_bf16((a), (b), (c), 0, 0, 0)
#define cfence() asm volatile("" ::: "memory")

__device__ __forceinline__ void gl_lds16(const void* gptr, void* lptr) {
    __builtin_amdgcn_global_load_lds(
        (const __attribute__((address_space(1))) unsigned int*)gptr,
        (__attribute__((address_space(3))) unsigned int*)lptr,
        16, 0, 0);
}

__device__ __forceinline__ unsigned short bf16_bits(float v) {
    __hip_bfloat16 h = __float2bfloat16(v);
    return *(unsigned short*)&h;
}

// ---------------------------------------------------------------------------
// prep: fused fp32->bf16 converts (blocks 0..3583) and bias precompute
// (blocks 3584..7679). biasS[b,g,i,j] = conv-bias * 0.125 bf16; masked ->
// 0xFF80 (bf16 -inf in-band magic).
// ---------------------------------------------------------------------------
__global__ __launch_bounds__(256) void prep(
    const float* __restrict__ q, const float* __restrict__ k, const float* __restrict__ v,
    const float* __restrict__ wq, const float* __restrict__ wk,
    const float* __restrict__ wv, const float* __restrict__ wo,
    const float* __restrict__ dist, const int* __restrict__ mask,
    const float* __restrict__ cw1, const float* __restrict__ cb1,
    const float* __restrict__ cw2, const float* __restrict__ cb2,
    __hip_bfloat16* qc, __hip_bfloat16* kc, __hip_bfloat16* vc,
    __hip_bfloat16* wqc, __hip_bfloat16* wkc, __hip_bfloat16* wvc, __hip_bfloat16* woc,
    __hip_bfloat16* __restrict__ biasS) {
    const int blk = blockIdx.x;
    if (blk >= 3584) {
        const int bi = blk - 3584;
        const int b = bi >> 10, i = bi & 1023;
        const int j0 = threadIdx.x * 4;
        const size_t dbase = ((size_t)b * 1024 + i) * 1024 + j0;
        float4 d4 = *(const float4*)(dist + dbase);
        int4 m4 = *(const int4*)(mask + dbase);
        float dv[4] = {d4.x, d4.y, d4.z, d4.w};
        int mv[4] = {m4.x, m4.y, m4.z, m4.w};
        float tt[4][8];
#pragma unroll
        for (int e = 0; e < 4; ++e)
#pragma unroll
            for (int h = 0; h < 8; ++h)
                tt[e][h] = fmaxf(fmaf(dv[e], cw1[h], cb1[h]), 0.f);
#pragma unroll
        for (int g = 0; g < 8; ++g) {
            const float c2 = cb2[g];
            union { unsigned short us[4]; uint2 u2; } o;
#pragma unroll
            for (int e = 0; e < 4; ++e) {
                float bv = c2;
#pragma unroll
                for (int h = 0; h < 8; ++h) bv = fmaf(tt[e][h], cw2[g * 8 + h], bv);
                unsigned short u = bf16_bits(bv * 0.125f);
                if (mv[e] == 0) u = 0xFF80u;
                o.us[e] = u;
            }
            *(uint2*)(biasS + ((size_t)(b * 8 + g) * 1024 + i) * 1024 + j0) = o.u2;
        }
        return;
    }
    const float* src;
    __hip_bfloat16* dst;
    int base;
    if (blk < 1024)      { src = q; dst = qc; base = blk; }
    else if (blk < 2048) { src = k; dst = kc; base = blk - 1024; }
    else if (blk < 3072) { src = v; dst = vc; base = blk - 2048; }
    else {
        const int wz = (blk - 3072) >> 7;
        base = (blk - 3072) & 127;
        switch (wz) {
            case 0: src = wq; dst = wqc; break;
            case 1: src = wk; dst = wkc; break;
            case 2: src = wv; dst = wvc; break;
            default: src = wo; dst = woc; break;
        }
    }
    const int idx = (base * 256 + threadIdx.x) * 8;
    float4 a = *(const float4*)(src + idx);
    float4 bb = *(const float4*)(src + idx + 4);
    union { __hip_bfloat16 h[8]; uint4 u; } o;
    o.h[0] = __float2bfloat16(a.x);  o.h[1] = __float2bfloat16(a.y);
    o.h[2] = __float2bfloat16(a.z);  o.h[3] = __float2bfloat16(a.w);
    o.h[4] = __float2bfloat16(bb.x); o.h[5] = __float2bfloat16(bb.y);
    o.h[6] = __float2bfloat16(bb.z); o.h[7] = __float2bfloat16(bb.w);
    *(uint4*)(dst + idx) = o.u;
}

// ---------------------------------------------------------------------------
// MFMA GEMM core, BK=128 (4 K-chunks), 256-B LDS rows, XOR-swizzle (mask 15).
// NROWS_W: W-tile rows (128 or 64). NT: n-tiles per wave (4 or 2).
// 4 waves in 2x2; wave = 64 x NT*16.
// ---------------------------------------------------------------------------
template <int NROWS_W, int NT>
__device__ __forceinline__ void gemm_core128(const __hip_bfloat16* A, const __hip_bfloat16* W,
                                             char* sA, char* sW, int m0, int n0,
                                             f32x4 acc[4][NT]) {
    const int t = threadIdx.x;
    const int w = t >> 6, lane = t & 63;
    const int wm = (w >> 1) * 64, wn = (w & 1) * (NT * 16);
    const int g = lane >> 4, ln = lane & 15;

    for (int kc = 0; kc < 4; ++kc) {
        __syncthreads();
        // A tile: 128 rows x 256 B = 32 KB -> 8 rounds
#pragma unroll
        for (int i = 0; i < 8; ++i) {
            int L = (i * 4 + w) * 64 + lane;
            int r = L >> 4, cs = L & 15;
            int c = cs ^ (r & 15);
            gl_lds16((const char*)A + (size_t)(m0 + r) * 1024 + kc * 256 + c * 16,
                     sA + (i * 4 + w) * 1024);
        }
        // W tile: NROWS_W rows x 256 B -> NROWS_W/16 rounds
#pragma unroll
        for (int i = 0; i < NROWS_W / 16; ++i) {
            int L = (i * 4 + w) * 64 + lane;
            int r = L >> 4, cs = L & 15;
            int c = cs ^ (r & 15);
            gl_lds16((const char*)W + (size_t)(n0 + r) * 1024 + kc * 256 + c * 16,
                     sW + (i * 4 + w) * 1024);
        }
        __syncthreads();
#pragma unroll
        for (int ks = 0; ks < 4; ++ks) {
            bf16x8 af[4], bf[NT];
#pragma unroll
            for (int mt = 0; mt < 4; ++mt) {
                int m = wm + mt * 16 + ln;
                int c = ks * 4 + g;
                af[mt] = *(const bf16x8*)(sA + m * 256 + (c ^ (m & 15)) * 16);
            }
#pragma unroll
            for (int nt = 0; nt < NT; ++nt) {
                int n = wn + nt * 16 + ln;
                int c = ks * 4 + g;
                bf[nt] = *(const bf16x8*)(sW + n * 256 + (c ^ (n & 15)) * 16);
            }
#pragma unroll
            for (int mt = 0; mt < 4; ++mt)
#pragma unroll
                for (int nt = 0; nt < NT; ++nt)
                    acc[mt][nt] = MFMA16(af[mt], bf[nt], acc[mt][nt]);
        }
    }
}

// Projections, 128x128 tiles. grid (4, 32, 3). z: 0=q, 1=k split-head
// [B,H,S,DK]; 2=v transposed [B,H,DK,S]. Two-pass LDS repack epilogue.
__global__ __launch_bounds__(256) void proj_gemm(
    const __hip_bfloat16* __restrict__ qc, const __hip_bfloat16* __restrict__ kc,
    const __hip_bfloat16* __restrict__ vc,
    const __hip_bfloat16* __restrict__ wqc, const __hip_bfloat16* __restrict__ wkc,
    const __hip_bfloat16* __restrict__ wvc,
    const float* __restrict__ bq, const float* __restrict__ bk, const float* __restrict__ bv,
    __hip_bfloat16* qbh, __hip_bfloat16* kbh, __hip_bfloat16* vt) {
    __shared__ char smem[65536];
    char* sA = smem;
    char* sW = smem + 32768;
    const int z = blockIdx.z;
    const __hip_bfloat16* A;
    const __hip_bfloat16* W;
    const float* bias;
    __hip_bfloat16* dst;
    if (z == 0)      { A = qc; W = wqc; bias = bq; dst = qbh; }
    else if (z == 1) { A = kc; W = wkc; bias = bk; dst = kbh; }
    else             { A = vc; W = wvc; bias = bv; dst = vt; }

    const int m0 = blockIdx.y * 128, n0 = blockIdx.x * 128;
    f32x4 acc[4][4] = {};
    gemm_core128<128, 4>(A, W, sA, sW, m0, n0, acc);
    __syncthreads();  // done with sA/sW; reuse for repack

    const int t = threadIdx.x;
    const int w = t >> 6, lane = t & 63;
    const int wm = (w >> 1) * 64, wn = (w & 1) * 64;
    const int g = lane >> 4, ln = lane & 15;
    const int b = m0 >> 10;
    float bv4[4];
#pragma unroll
    for (int nt = 0; nt < 4; ++nt) bv4[nt] = bias[n0 + wn + nt * 16 + ln];

    __hip_bfloat16* T = (__hip_bfloat16*)smem;
    if (z != 2) {
        // rows padded to 136 bf16 (272 B, 16B-aligned for b128 reads)
#pragma unroll
        for (int p = 0; p < 2; ++p) {
            if (wm == p * 64) {
#pragma unroll
                for (int mt = 0; mt < 4; ++mt)
#pragma unroll
                    for (int nt = 0; nt < 4; ++nt)
#pragma unroll
                        for (int r = 0; r < 4; ++r)
                            T[(mt * 16 + g * 4 + r) * 136 + wn + nt * 16 + ln] =
                                __float2bfloat16(acc[mt][nt][r] + bv4[nt]);
            }
            __syncthreads();
            const int lr = t >> 2, quarter = t & 3;
            const char* srow = (const char*)T + lr * 272 + quarter * 64;
            const int s = (m0 & 1023) + p * 64 + lr;
            const int h = (n0 >> 6) + (quarter >> 1);
            char* gdst = (char*)dst +
                         (((size_t)(b * 8 + h) * 1024 + s) * 64 + (quarter & 1) * 32) * 2;
#pragma unroll
            for (int j = 0; j < 4; ++j)
                *(uint4*)(gdst + j * 16) = *(const uint4*)(srow + j * 16);
            __syncthreads();
        }
    } else {
        // rows padded to 130 bf16 (260 B, odd word stride -> conflict-free cols)
#pragma unroll
        for (int p = 0; p < 2; ++p) {
            if (wm == p * 64) {
#pragma unroll
                for (int mt = 0; mt < 4; ++mt)
#pragma unroll
                    for (int nt = 0; nt < 4; ++nt)
#pragma unroll
                        for (int r = 0; r < 4; ++r)
                            T[(mt * 16 + g * 4 + r) * 130 + wn + nt * 16 + ln] =
                                __float2bfloat16(acc[mt][nt][r] + bv4[nt]);
            }
            __syncthreads();
            const int c = t >> 1, sel = t & 1;
            union { __hip_bfloat16 h[32]; uint4 u[4]; } P;
#pragma unroll
            for (int i = 0; i < 32; ++i)
                P.h[i] = T[(sel * 32 + i) * 130 + c];
            const int h = (n0 >> 6) + (c >> 6), dk = c & 63;
            char* gdst = (char*)vt +
                         (((size_t)(b * 8 + h) * 64 + dk) * 1024 + (m0 & 1023) + p * 64 + sel * 32) * 2;
#pragma unroll
            for (int j = 0; j < 4; ++j)
                *(uint4*)(gdst + j * 16) = P.u[j];
            __syncthreads();
        }
    }
}

// Output GEMM: out[4096,512] fp32, 128x64 tile, BK=128. grid (8, 32).
__global__ __launch_bounds__(256) void out_gemm(
    const __hip_bfloat16* __restrict__ X, const __hip_bfloat16* __restrict__ woc,
    const float* __restrict__ bo, float* __restrict__ out) {
    __shared__ char smem[49152];
    char* sA = smem;
    char* sW = smem + 32768;
    const int m0 = blockIdx.y * 128, n0 = blockIdx.x * 64;
    f32x4 acc[4][2] = {};
    gemm_core128<64, 2>(X, woc, sA, sW, m0, n0, acc);

    const int t = threadIdx.x;
    const int w = t >> 6, lane = t & 63;
    const int wm = (w >> 1) * 64, wn = (w & 1) * 32;
    const int g = lane >> 4, ln = lane & 15;
    float bv2[2];
#pragma unroll
    for (int nt = 0; nt < 2; ++nt) bv2[nt] = bo[n0 + wn + nt * 16 + ln];
#pragma unroll
    for (int mt = 0; mt < 4; ++mt)
#pragma unroll
        for (int nt = 0; nt < 2; ++nt)
#pragma unroll
            for (int r = 0; r < 4; ++r) {
                int m = m0 + wm + mt * 16 + g * 4 + r;
                int f = n0 + wn + nt * 16 + ln;
                out[(size_t)m * 512 + f] = acc[mt][nt][r] + bv2[nt];
            }
}

// ---------------------------------------------------------------------------
// MFMA flash attention, precomputed bias, 128-key tiles (two softmax
// sub-phases per load -> half the barrier drains). grid (16, 32).
// ---------------------------------------------------------------------------
__global__ __launch_bounds__(256) void attn(
    const __hip_bfloat16* __restrict__ Qb, const __hip_bfloat16* __restrict__ Kb,
    const __hip_bfloat16* __restrict__ Vt, const __hip_bfloat16* __restrict__ biasS,
    __hip_bfloat16* __restrict__ X) {
    __shared__ char sK[16384];       // 128 keys x 128 B
    __shared__ char sV[16384];       // 64 dk x 256 B (128-key window)
    __shared__ char sScP[4][4352];   // per-wave: f32 scores 16x66 OR bf16 P 16x72
    __shared__ float sBr[4][16];

    const int t = threadIdx.x, w = t >> 6, lane = t & 63;
    const int g = lane >> 4, ln = lane & 15;
    const int qr = lane >> 2, a = lane & 3;
    const int bh = blockIdx.y;
    const int q0 = blockIdx.x * 64;

    float* sc = (float*)(sScP[w]);
    __hip_bfloat16* sp = (__hip_bfloat16*)(sScP[w]);

    bf16x8 qf[2];
    {
        const char* qbase = (const char*)Qb + ((size_t)bh * 1024 + q0 + w * 16 + ln) * 128;
        qf[0] = *(const bf16x8*)(qbase + g * 16);
        qf[1] = *(const bf16x8*)(qbase + 64 + g * 16);
    }

    float m_st = -1e30f, l_st = 0.f;
    f32x4 O[4] = {};

    const size_t kbase = (size_t)bh * 1024 * 128;
    const size_t vbase = (size_t)bh * 64 * 2048;
    const __hip_bfloat16* brow = biasS + ((size_t)bh * 1024 + q0 + w * 16 + qr) * 1024;

    for (int kt = 0; kt < S_; kt += 128) {
        __syncthreads();
        // K tile: 4 rounds (128-B rows, swizzle mask 7)
#pragma unroll
        for (int i = 0; i < 4; ++i) {
            int L = (i * 4 + w) * 64 + lane;
            int r = L >> 3, cs = L & 7;
            int c = cs ^ (r & 7);
            gl_lds16((const char*)Kb + kbase + (size_t)(kt + r) * 128 + c * 16,
                     sK + (i * 4 + w) * 1024);
        }
        // V tile: 4 rounds (256-B rows, swizzle mask 15)
#pragma unroll
        for (int i = 0; i < 4; ++i) {
            int L = (i * 4 + w) * 64 + lane;
            int r = L >> 4, cs = L & 15;
            int c = cs ^ (r & 15);
            gl_lds16((const char*)Vt + vbase + (size_t)r * 2048 + (size_t)kt * 2 + c * 16,
                     sV + (i * 4 + w) * 1024);
        }
        // bias prefetch, both halves
        union { uint4 u[2]; unsigned short us[16]; } bb[2];
#pragma unroll
        for (int ph = 0; ph < 2; ++ph) {
            bb[ph].u[0] = *(const uint4*)(brow + kt + ph * 64 + a * 16);
            bb[ph].u[1] = *(const uint4*)(brow + kt + ph * 64 + a * 16 + 8);
        }
        __syncthreads();

#pragma unroll
        for (int ph = 0; ph < 2; ++ph) {
            // QK^T for this 64-key half
            f32x4 scv[4] = {};
#pragma unroll
            for (int tt = 0; tt < 4; ++tt)
#pragma unroll
                for (int ks = 0; ks < 2; ++ks) {
                    int key = ph * 64 + tt * 16 + ln;
                    int c = ks * 4 + g;
                    bf16x8 kf = *(const bf16x8*)(sK + key * 128 + (c ^ (key & 7)) * 16);
                    scv[tt] = MFMA16(qf[ks], kf, scv[tt]);
                }

            cfence();
#pragma unroll
            for (int tt = 0; tt < 4; ++tt)
#pragma unroll
                for (int r = 0; r < 4; ++r)
                    sc[(g * 4 + r) * 66 + tt * 16 + ln] = scv[tt][r];
            cfence();

            float sr[16];
            {
                const float* scrow = sc + qr * 66 + a * 16;
#pragma unroll
                for (int j = 0; j < 8; ++j) {
                    float2 v2 = *(const float2*)(scrow + j * 2);
                    sr[j * 2] = v2.x; sr[j * 2 + 1] = v2.y;
                }
            }
            cfence();

            float mx = -1e30f;
#pragma unroll
            for (int e = 0; e < 16; ++e) {
                unsigned int bits = bb[ph].us[e];
                float f = __uint_as_float(bits << 16);
                float s = sr[e] * f;
                s = (bits == 0xFF80u) ? -1e9f : s;
                sr[e] = s;
                mx = fmaxf(mx, s);
            }
            mx = fmaxf(mx, __shfl_xor(mx, 1));
            mx = fmaxf(mx, __shfl_xor(mx, 2));
            const float mnew = fmaxf(m_st, mx);
            const float alpha = __expf(m_st - mnew);
            m_st = mnew;
            float rs = 0.f;
            union { __hip_bfloat16 hh16[16]; uint4 u[2]; } Pk;
#pragma unroll
            for (int i = 0; i < 16; ++i) {
                float p = __expf(sr[i] - mnew);
                rs += p;
                Pk.hh16[i] = __float2bfloat16(p);
            }
            rs += __shfl_xor(rs, 1);
            rs += __shfl_xor(rs, 2);
            l_st = l_st * alpha + rs;

            *(uint4*)(sp + qr * 72 + a * 16) = Pk.u[0];
            *(uint4*)(sp + qr * 72 + a * 16 + 8) = Pk.u[1];
            cfence();

            if (a == 0) sBr[w][qr] = alpha;
            float al4[4];
#pragma unroll
            for (int r = 0; r < 4; ++r) al4[r] = sBr[w][g * 4 + r];
#pragma unroll
            for (int tt = 0; tt < 4; ++tt)
#pragma unroll
                for (int r = 0; r < 4; ++r) O[tt][r] *= al4[r];

            // PV for this half: V chunks ck = ph*8 + ks*4 + g
#pragma unroll
            for (int ks = 0; ks < 2; ++ks) {
                bf16x8 pf = *(const bf16x8*)(sp + ln * 72 + ks * 32 + g * 8);
#pragma unroll
                for (int tt = 0; tt < 4; ++tt) {
                    int dk = tt * 16 + ln;
                    int ck = ph * 8 + ks * 4 + g;
                    bf16x8 vf = *(const bf16x8*)(sV + dk * 256 + (ck ^ (dk & 15)) * 16);
                    O[tt] = MFMA16(pf, vf, O[tt]);
                }
            }
            cfence();
        }
    }

    if (a == 0) sBr[w][qr] = l_st;
    __builtin_amdgcn_s_waitcnt(0);
    const int b = bh >> 3, h = bh & 7;
#pragma unroll
    for (int r = 0; r < 4; ++r) {
        float inv = 1.f / sBr[w][g * 4 + r];
        int q = q0 + w * 16 + g * 4 + r;
#pragma unroll
        for (int tt = 0; tt < 4; ++tt) {
            int dk = tt * 16 + ln;
            X[((size_t)(b * 1024 + q)) * 512 + h * 64 + dk] = __float2bfloat16(O[tt][r] * inv);
        }
    }
}

extern "C" void kernel_launch(void* const* d_in, const int* in_sizes, int n_in,
                              void* d_out, int out_size, void* d_ws, size_t ws_size,
                              hipStream_t stream) {
    (void)in_sizes; (void)n_in; (void)out_size; (void)ws_size;
    const float* query = (const float*)d_in[0];
    const float* key   = (const float*)d_in[1];
    const float* value = (const float*)d_in[2];
    const float* dist  = (const float*)d_in[3];
    const int*   mask  = (const int*)d_in[4];
    const float* Wq = (const float*)d_in[5];
    const float* bq = (const float*)d_in[6];
    const float* Wk = (const float*)d_in[7];
    const float* bk = (const float*)d_in[8];
    const float* Wv = (const float*)d_in[9];
    const float* bv = (const float*)d_in[10];
    const float* Wo = (const float*)d_in[11];
    const float* bo = (const float*)d_in[12];
    const float* cw1 = (const float*)d_in[13];
    const float* cb1 = (const float*)d_in[14];
    const float* cw2 = (const float*)d_in[15];
    const float* cb2 = (const float*)d_in[16];
    float* out = (float*)d_out;

    char* ws = (char*)d_ws;
    const size_t MB = 1 << 20;
    __hip_bfloat16* qc  = (__hip_bfloat16*)(ws + 0 * MB);
    __hip_bfloat16* kc  = (__hip_bfloat16*)(ws + 4 * MB);
    __hip_bfloat16* vc  = (__hip_bfloat16*)(ws + 8 * MB);
    __hip_bfloat16* wqc = (__hip_bfloat16*)(ws + 12 * MB);
    __hip_bfloat16* wkc = (__hip_bfloat16*)(ws + 12 * MB + 512 * 1024);
    __hip_bfloat16* wvc = (__hip_bfloat16*)(ws + 13 * MB);
    __hip_bfloat16* woc = (__hip_bfloat16*)(ws + 13 * MB + 512 * 1024);
    __hip_bfloat16* qbh = (__hip_bfloat16*)(ws + 14 * MB);
    __hip_bfloat16* kbh = (__hip_bfloat16*)(ws + 18 * MB);
    __hip_bfloat16* vt  = (__hip_bfloat16*)(ws + 22 * MB);
    __hip_bfloat16* x   = (__hip_bfloat16*)(ws + 26 * MB);
    __hip_bfloat16* bS  = (__hip_bfloat16*)(ws + 32 * MB);  // 64 MB

    hipLaunchKernelGGL(prep, dim3(7680), dim3(256), 0, stream,
                       query, key, value, Wq, Wk, Wv, Wo, dist, mask,
                       cw1, cb1, cw2, cb2,
                       qc, kc, vc, wqc, wkc, wvc, woc, bS);
    hipLaunchKernelGGL(proj_gemm, dim3(4, 32, 3), dim3(256), 0, stream,
                       qc, kc, vc, wqc, wkc, wvc, bq, bk, bv, qbh, kbh, vt);
    hipLaunchKernelGGL(attn, dim3(16, 32), dim3(256), 0, stream,
                       qbh, kbh, vt, bS, x);
    hipLaunchKernelGGL(out_gemm, dim3(8, 32), dim3(256), 0, stream,
                       x, woc, bo, out);
}

// Round 7
// 196.125 us; speedup vs baseline: 3.0604x; 1.0086x over previous
//
#include <hip/hip_runtime.h>
#include <hip/hip_bf16.h>
#include <math.h>

#define B_ 4
#define S_ 1024
#define E_ 512
#define H_ 8
#define DK_ 64

typedef short bf16x8 __attribute__((ext_vector_type(8)));
typedef float f32x4 __attribute__((ext_vector_type(4)));

#define MFMA16(a, b, c) __builtin_amdgcn_mfma_f32_16x16x32_bf16((a), (b), (c), 0, 0, 0)
#define cfence() asm volatile("" ::: "memory")

__device__ __forceinline__ void gl_lds16(const void* gptr, void* lptr) {
    __builtin_amdgcn_global_load_lds(
        (const __attribute__((address_space(1))) unsigned int*)gptr,
        (__attribute__((address_space(3))) unsigned int*)lptr,
        16, 0, 0);
}

__device__ __forceinline__ unsigned short bf16_bits(float v) {
    __hip_bfloat16 h = __float2bfloat16(v);
    return *(unsigned short*)&h;
}

// ---------------------------------------------------------------------------
// prep: fused fp32->bf16 converts (blocks 0..3583) and bias precompute
// (blocks 3584..7679). biasS[b,g,i,j] = conv-bias * 0.125 bf16; masked ->
// 0xFF80 (bf16 -inf in-band magic).
// ---------------------------------------------------------------------------
__global__ __launch_bounds__(256) void prep(
    const float* __restrict__ q, const float* __restrict__ k, const float* __restrict__ v,
    const float* __restrict__ wq, const float* __restrict__ wk,
    const float* __restrict__ wv, const float* __restrict__ wo,
    const float* __restrict__ dist, const int* __restrict__ mask,
    const float* __restrict__ cw1, const float* __restrict__ cb1,
    const float* __restrict__ cw2, const float* __restrict__ cb2,
    __hip_bfloat16* qc, __hip_bfloat16* kc, __hip_bfloat16* vc,
    __hip_bfloat16* wqc, __hip_bfloat16* wkc, __hip_bfloat16* wvc, __hip_bfloat16* woc,
    __hip_bfloat16* __restrict__ biasS) {
    const int blk = blockIdx.x;
    if (blk >= 3584) {
        const int bi = blk - 3584;
        const int b = bi >> 10, i = bi & 1023;
        const int j0 = threadIdx.x * 4;
        const size_t dbase = ((size_t)b * 1024 + i) * 1024 + j0;
        float4 d4 = *(const float4*)(dist + dbase);
        int4 m4 = *(const int4*)(mask + dbase);
        float dv[4] = {d4.x, d4.y, d4.z, d4.w};
        int mv[4] = {m4.x, m4.y, m4.z, m4.w};
        float tt[4][8];
#pragma unroll
        for (int e = 0; e < 4; ++e)
#pragma unroll
            for (int h = 0; h < 8; ++h)
                tt[e][h] = fmaxf(fmaf(dv[e], cw1[h], cb1[h]), 0.f);
#pragma unroll
        for (int g = 0; g < 8; ++g) {
            const float c2 = cb2[g];
            union { unsigned short us[4]; uint2 u2; } o;
#pragma unroll
            for (int e = 0; e < 4; ++e) {
                float bv = c2;
#pragma unroll
                for (int h = 0; h < 8; ++h) bv = fmaf(tt[e][h], cw2[g * 8 + h], bv);
                unsigned short u = bf16_bits(bv * 0.125f);
                if (mv[e] == 0) u = 0xFF80u;
                o.us[e] = u;
            }
            *(uint2*)(biasS + ((size_t)(b * 8 + g) * 1024 + i) * 1024 + j0) = o.u2;
        }
        return;
    }
    const float* src;
    __hip_bfloat16* dst;
    int base;
    if (blk < 1024)      { src = q; dst = qc; base = blk; }
    else if (blk < 2048) { src = k; dst = kc; base = blk - 1024; }
    else if (blk < 3072) { src = v; dst = vc; base = blk - 2048; }
    else {
        const int wz = (blk - 3072) >> 7;
        base = (blk - 3072) & 127;
        switch (wz) {
            case 0: src = wq; dst = wqc; break;
            case 1: src = wk; dst = wkc; break;
            case 2: src = wv; dst = wvc; break;
            default: src = wo; dst = woc; break;
        }
    }
    const int idx = (base * 256 + threadIdx.x) * 8;
    float4 a = *(const float4*)(src + idx);
    float4 bb = *(const float4*)(src + idx + 4);
    union { __hip_bfloat16 h[8]; uint4 u; } o;
    o.h[0] = __float2bfloat16(a.x);  o.h[1] = __float2bfloat16(a.y);
    o.h[2] = __float2bfloat16(a.z);  o.h[3] = __float2bfloat16(a.w);
    o.h[4] = __float2bfloat16(bb.x); o.h[5] = __float2bfloat16(bb.y);
    o.h[6] = __float2bfloat16(bb.z); o.h[7] = __float2bfloat16(bb.w);
    *(uint4*)(dst + idx) = o.u;
}

// ---------------------------------------------------------------------------
// MFMA GEMM core, BK=128 (4 K-chunks), 256-B LDS rows, XOR-swizzle (mask 15).
// ---------------------------------------------------------------------------
template <int NROWS_W, int NT>
__device__ __forceinline__ void gemm_core128(const __hip_bfloat16* A, const __hip_bfloat16* W,
                                             char* sA, char* sW, int m0, int n0,
                                             f32x4 acc[4][NT]) {
    const int t = threadIdx.x;
    const int w = t >> 6, lane = t & 63;
    const int wm = (w >> 1) * 64, wn = (w & 1) * (NT * 16);
    const int g = lane >> 4, ln = lane & 15;

    for (int kc = 0; kc < 4; ++kc) {
        __syncthreads();
#pragma unroll
        for (int i = 0; i < 8; ++i) {
            int L = (i * 4 + w) * 64 + lane;
            int r = L >> 4, cs = L & 15;
            int c = cs ^ (r & 15);
            gl_lds16((const char*)A + (size_t)(m0 + r) * 1024 + kc * 256 + c * 16,
                     sA + (i * 4 + w) * 1024);
        }
#pragma unroll
        for (int i = 0; i < NROWS_W / 16; ++i) {
            int L = (i * 4 + w) * 64 + lane;
            int r = L >> 4, cs = L & 15;
            int c = cs ^ (r & 15);
            gl_lds16((const char*)W + (size_t)(n0 + r) * 1024 + kc * 256 + c * 16,
                     sW + (i * 4 + w) * 1024);
        }
        __syncthreads();
#pragma unroll
        for (int ks = 0; ks < 4; ++ks) {
            bf16x8 af[4], bf[NT];
#pragma unroll
            for (int mt = 0; mt < 4; ++mt) {
                int m = wm + mt * 16 + ln;
                int c = ks * 4 + g;
                af[mt] = *(const bf16x8*)(sA + m * 256 + (c ^ (m & 15)) * 16);
            }
#pragma unroll
            for (int nt = 0; nt < NT; ++nt) {
                int n = wn + nt * 16 + ln;
                int c = ks * 4 + g;
                bf[nt] = *(const bf16x8*)(sW + n * 256 + (c ^ (n & 15)) * 16);
            }
#pragma unroll
            for (int mt = 0; mt < 4; ++mt)
#pragma unroll
                for (int nt = 0; nt < NT; ++nt)
                    acc[mt][nt] = MFMA16(af[mt], bf[nt], acc[mt][nt]);
        }
    }
}

// Projections, 128x128 tiles. grid (4, 32, 3). z: 0=q, 1=k split-head
// [B,H,S,DK]; 2=v transposed [B,H,DK,S]. Two-pass LDS repack epilogue.
__global__ __launch_bounds__(256) void proj_gemm(
    const __hip_bfloat16* __restrict__ qc, const __hip_bfloat16* __restrict__ kc,
    const __hip_bfloat16* __restrict__ vc,
    const __hip_bfloat16* __restrict__ wqc, const __hip_bfloat16* __restrict__ wkc,
    const __hip_bfloat16* __restrict__ wvc,
    const float* __restrict__ bq, const float* __restrict__ bk, const float* __restrict__ bv,
    __hip_bfloat16* qbh, __hip_bfloat16* kbh, __hip_bfloat16* vt) {
    __shared__ char smem[65536];
    char* sA = smem;
    char* sW = smem + 32768;
    const int z = blockIdx.z;
    const __hip_bfloat16* A;
    const __hip_bfloat16* W;
    const float* bias;
    __hip_bfloat16* dst;
    if (z == 0)      { A = qc; W = wqc; bias = bq; dst = qbh; }
    else if (z == 1) { A = kc; W = wkc; bias = bk; dst = kbh; }
    else             { A = vc; W = wvc; bias = bv; dst = vt; }

    const int m0 = blockIdx.y * 128, n0 = blockIdx.x * 128;
    f32x4 acc[4][4] = {};
    gemm_core128<128, 4>(A, W, sA, sW, m0, n0, acc);
    __syncthreads();

    const int t = threadIdx.x;
    const int w = t >> 6, lane = t & 63;
    const int wm = (w >> 1) * 64, wn = (w & 1) * 64;
    const int g = lane >> 4, ln = lane & 15;
    const int b = m0 >> 10;
    float bv4[4];
#pragma unroll
    for (int nt = 0; nt < 4; ++nt) bv4[nt] = bias[n0 + wn + nt * 16 + ln];

    __hip_bfloat16* T = (__hip_bfloat16*)smem;
    if (z != 2) {
#pragma unroll
        for (int p = 0; p < 2; ++p) {
            if (wm == p * 64) {
#pragma unroll
                for (int mt = 0; mt < 4; ++mt)
#pragma unroll
                    for (int nt = 0; nt < 4; ++nt)
#pragma unroll
                        for (int r = 0; r < 4; ++r)
                            T[(mt * 16 + g * 4 + r) * 136 + wn + nt * 16 + ln] =
                                __float2bfloat16(acc[mt][nt][r] + bv4[nt]);
            }
            __syncthreads();
            const int lr = t >> 2, quarter = t & 3;
            const char* srow = (const char*)T + lr * 272 + quarter * 64;
            const int s = (m0 & 1023) + p * 64 + lr;
            const int h = (n0 >> 6) + (quarter >> 1);
            char* gdst = (char*)dst +
                         (((size_t)(b * 8 + h) * 1024 + s) * 64 + (quarter & 1) * 32) * 2;
#pragma unroll
            for (int j = 0; j < 4; ++j)
                *(uint4*)(gdst + j * 16) = *(const uint4*)(srow + j * 16);
            __syncthreads();
        }
    } else {
#pragma unroll
        for (int p = 0; p < 2; ++p) {
            if (wm == p * 64) {
#pragma unroll
                for (int mt = 0; mt < 4; ++mt)
#pragma unroll
                    for (int nt = 0; nt < 4; ++nt)
#pragma unroll
                        for (int r = 0; r < 4; ++r)
                            T[(mt * 16 + g * 4 + r) * 130 + wn + nt * 16 + ln] =
                                __float2bfloat16(acc[mt][nt][r] + bv4[nt]);
            }
            __syncthreads();
            const int c = t >> 1, sel = t & 1;
            union { __hip_bfloat16 h[32]; uint4 u[4]; } P;
#pragma unroll
            for (int i = 0; i < 32; ++i)
                P.h[i] = T[(sel * 32 + i) * 130 + c];
            const int h = (n0 >> 6) + (c >> 6), dk = c & 63;
            char* gdst = (char*)vt +
                         (((size_t)(b * 8 + h) * 64 + dk) * 1024 + (m0 & 1023) + p * 64 + sel * 32) * 2;
#pragma unroll
            for (int j = 0; j < 4; ++j)
                *(uint4*)(gdst + j * 16) = P.u[j];
            __syncthreads();
        }
    }
}

// Output GEMM: out[4096,512] fp32, 128x64 tile, BK=128. grid (8, 32).
__global__ __launch_bounds__(256) void out_gemm(
    const __hip_bfloat16* __restrict__ X, const __hip_bfloat16* __restrict__ woc,
    const float* __restrict__ bo, float* __restrict__ out) {
    __shared__ char smem[49152];
    char* sA = smem;
    char* sW = smem + 32768;
    const int m0 = blockIdx.y * 128, n0 = blockIdx.x * 64;
    f32x4 acc[4][2] = {};
    gemm_core128<64, 2>(X, woc, sA, sW, m0, n0, acc);

    const int t = threadIdx.x;
    const int w = t >> 6, lane = t & 63;
    const int wm = (w >> 1) * 64, wn = (w & 1) * 32;
    const int g = lane >> 4, ln = lane & 15;
    float bv2[2];
#pragma unroll
    for (int nt = 0; nt < 2; ++nt) bv2[nt] = bo[n0 + wn + nt * 16 + ln];
#pragma unroll
    for (int mt = 0; mt < 4; ++mt)
#pragma unroll
        for (int nt = 0; nt < 2; ++nt)
#pragma unroll
            for (int r = 0; r < 4; ++r) {
                int m = m0 + wm + mt * 16 + g * 4 + r;
                int f = n0 + wn + nt * 16 + ln;
                out[(size_t)m * 512 + f] = acc[mt][nt][r] + bv2[nt];
            }
}

// ---------------------------------------------------------------------------
// Flash-decode split-K attention. grid (16, 32, 2): (q-tile, b*h, key-split).
// Each block: 512 keys in 8x64-key tiles. LDS 34 KB -> 4 blocks/CU.
// Partial unnormalized O (f32) + (m,l) to workspace; combine merges.
// ---------------------------------------------------------------------------
__global__ __launch_bounds__(256) void attn_split(
    const __hip_bfloat16* __restrict__ Qb, const __hip_bfloat16* __restrict__ Kb,
    const __hip_bfloat16* __restrict__ Vt, const __hip_bfloat16* __restrict__ biasS,
    float* __restrict__ Op, float2* __restrict__ Ml) {
    __shared__ char sK[8192];        // 64 keys x 128 B
    __shared__ char sV[8192];        // 64 dk x 128 B window
    __shared__ char sScP[4][4352];   // per-wave: f32 scores 16x66 OR bf16 P 16x72
    __shared__ float sBr[4][16];

    const int t = threadIdx.x, w = t >> 6, lane = t & 63;
    const int g = lane >> 4, ln = lane & 15;
    const int qr = lane >> 2, a = lane & 3;
    const int bh = blockIdx.y;
    const int q0 = blockIdx.x * 64;
    const int spl = blockIdx.z;
    const int kt0 = spl * 512;

    float* sc = (float*)(sScP[w]);
    __hip_bfloat16* sp = (__hip_bfloat16*)(sScP[w]);

    bf16x8 qf[2];
    {
        const char* qbase = (const char*)Qb + ((size_t)bh * 1024 + q0 + w * 16 + ln) * 128;
        qf[0] = *(const bf16x8*)(qbase + g * 16);
        qf[1] = *(const bf16x8*)(qbase + 64 + g * 16);
    }

    // hoisted K/V/bias addresses (incremented each iteration)
    const char* kaddr[2];
    const char* vaddr[2];
#pragma unroll
    for (int i = 0; i < 2; ++i) {
        int L = (i * 4 + w) * 64 + lane;
        int r = L >> 3, cs = L & 7;
        int c = cs ^ (r & 7);
        kaddr[i] = (const char*)Kb + (size_t)bh * 131072 + (size_t)(kt0 + r) * 128 + c * 16;
        vaddr[i] = (const char*)Vt + (size_t)bh * 131072 + (size_t)r * 2048 + (size_t)kt0 * 2 + c * 16;
    }
    const char* baddr =
        (const char*)(biasS + ((size_t)bh * 1024 + q0 + w * 16 + qr) * 1024 + kt0 + a * 16);

    float m_st = -1e30f, l_st = 0.f;
    f32x4 O[4] = {};

    for (int it = 0; it < 8; ++it) {
        __syncthreads();
#pragma unroll
        for (int i = 0; i < 2; ++i) {
            gl_lds16(kaddr[i], sK + (i * 4 + w) * 1024);
            gl_lds16(vaddr[i], sV + (i * 4 + w) * 1024);
            kaddr[i] += 8192;   // 64 keys * 128 B
            vaddr[i] += 128;    // 64 keys * 2 B within each Vt row
        }
        union { uint4 u[2]; unsigned short us[16]; } bb;
        bb.u[0] = *(const uint4*)baddr;
        bb.u[1] = *(const uint4*)(baddr + 16);  // FIX: +16 bytes (was +64)
        baddr += 128;
        __syncthreads();

        // QK^T (C-layout)
        f32x4 scv[4] = {};
#pragma unroll
        for (int tt = 0; tt < 4; ++tt)
#pragma unroll
            for (int ks = 0; ks < 2; ++ks) {
                int key = tt * 16 + ln;
                int c = ks * 4 + g;
                bf16x8 kf = *(const bf16x8*)(sK + key * 128 + (c ^ (key & 7)) * 16);
                scv[tt] = MFMA16(qf[ks], kf, scv[tt]);
            }

        cfence();
#pragma unroll
        for (int tt = 0; tt < 4; ++tt)
#pragma unroll
            for (int r = 0; r < 4; ++r)
                sc[(g * 4 + r) * 66 + tt * 16 + ln] = scv[tt][r];
        cfence();

        float sr[16];
        {
            const float* scrow = sc + qr * 66 + a * 16;
#pragma unroll
            for (int j = 0; j < 8; ++j) {
                float2 v2 = *(const float2*)(scrow + j * 2);
                sr[j * 2] = v2.x; sr[j * 2 + 1] = v2.y;
            }
        }
        cfence();

        float mx = -1e30f;
#pragma unroll
        for (int e = 0; e < 16; ++e) {
            unsigned int bits = bb.us[e];
            float f = __uint_as_float(bits << 16);
            float s = sr[e] * f;
            s = (bits == 0xFF80u) ? -1e9f : s;
            sr[e] = s;
            mx = fmaxf(mx, s);
        }
        mx = fmaxf(mx, __shfl_xor(mx, 1));
        mx = fmaxf(mx, __shfl_xor(mx, 2));
        const float mnew = fmaxf(m_st, mx);
        const float alpha = __expf(m_st - mnew);
        m_st = mnew;
        float rs = 0.f;
        union { __hip_bfloat16 hh16[16]; uint4 u[2]; } Pk;
#pragma unroll
        for (int i = 0; i < 16; ++i) {
            float p = __expf(sr[i] - mnew);
            rs += p;
            Pk.hh16[i] = __float2bfloat16(p);
        }
        rs += __shfl_xor(rs, 1);
        rs += __shfl_xor(rs, 2);
        l_st = l_st * alpha + rs;

        *(uint4*)(sp + qr * 72 + a * 16) = Pk.u[0];
        *(uint4*)(sp + qr * 72 + a * 16 + 8) = Pk.u[1];
        cfence();

        if (a == 0) sBr[w][qr] = alpha;
        float al4[4];
#pragma unroll
        for (int r = 0; r < 4; ++r) al4[r] = sBr[w][g * 4 + r];
#pragma unroll
        for (int tt = 0; tt < 4; ++tt)
#pragma unroll
            for (int r = 0; r < 4; ++r) O[tt][r] *= al4[r];

        // PV
#pragma unroll
        for (int ks = 0; ks < 2; ++ks) {
            bf16x8 pf = *(const bf16x8*)(sp + ln * 72 + ks * 32 + g * 8);
#pragma unroll
            for (int tt = 0; tt < 4; ++tt) {
                int dk = tt * 16 + ln;
                int c = ks * 4 + g;
                bf16x8 vf = *(const bf16x8*)(sV + dk * 128 + (c ^ (dk & 7)) * 16);
                O[tt] = MFMA16(pf, vf, O[tt]);
            }
        }
        cfence();
    }

    // partial epilogue: unnormalized O (f32) + (m,l) per row
    const size_t rowbase = ((size_t)spl * 32 + bh) * 1024 + q0 + w * 16;
    if (a == 0) {
        float2 ml2; ml2.x = m_st; ml2.y = l_st;
        Ml[rowbase + qr] = ml2;
    }
#pragma unroll
    for (int r = 0; r < 4; ++r) {
        const int q = g * 4 + r;
#pragma unroll
        for (int tt = 0; tt < 4; ++tt)
            Op[(rowbase + q) * 64 + tt * 16 + ln] = O[tt][r];
    }
}

// Merge the two key-splits. grid 4096 x 256 thr; thread = (row, dk pair).
__global__ __launch_bounds__(256) void combine(
    const float* __restrict__ Op, const float2* __restrict__ Ml,
    __hip_bfloat16* __restrict__ X) {
    const int idx = blockIdx.x * 256 + threadIdx.x;
    const int row = idx >> 5;
    const int pr = (idx & 31) * 2;
    float2 ml1 = Ml[row], ml2 = Ml[32768 + row];
    float m = fmaxf(ml1.x, ml2.x);
    float w1 = __expf(ml1.x - m), w2 = __expf(ml2.x - m);
    float inv = 1.f / fmaf(ml1.y, w1, ml2.y * w2);
    float2 o1 = *(const float2*)(Op + (size_t)row * 64 + pr);
    float2 o2 = *(const float2*)(Op + ((size_t)32768 + row) * 64 + pr);
    float x0 = fmaf(o1.x, w1, o2.x * w2) * inv;
    float x1 = fmaf(o1.y, w1, o2.y * w2) * inv;
    const int bh = row >> 10, s = row & 1023, b = bh >> 3, h = bh & 7;
    union { __hip_bfloat16 hh[2]; unsigned int u; } o;
    o.hh[0] = __float2bfloat16(x0);
    o.hh[1] = __float2bfloat16(x1);
    *(unsigned int*)(X + ((size_t)(b * 1024 + s)) * 512 + h * 64 + pr) = o.u;
}

extern "C" void kernel_launch(void* const* d_in, const int* in_sizes, int n_in,
                              void* d_out, int out_size, void* d_ws, size_t ws_size,
                              hipStream_t stream) {
    (void)in_sizes; (void)n_in; (void)out_size; (void)ws_size;
    const float* query = (const float*)d_in[0];
    const float* key   = (const float*)d_in[1];
    const float* value = (const float*)d_in[2];
    const float* dist  = (const float*)d_in[3];
    const int*   mask  = (const int*)d_in[4];
    const float* Wq = (const float*)d_in[5];
    const float* bq = (const float*)d_in[6];
    const float* Wk = (const float*)d_in[7];
    const float* bk = (const float*)d_in[8];
    const float* Wv = (const float*)d_in[9];
    const float* bv = (const float*)d_in[10];
    const float* Wo = (const float*)d_in[11];
    const float* bo = (const float*)d_in[12];
    const float* cw1 = (const float*)d_in[13];
    const float* cb1 = (const float*)d_in[14];
    const float* cw2 = (const float*)d_in[15];
    const float* cb2 = (const float*)d_in[16];
    float* out = (float*)d_out;

    char* ws = (char*)d_ws;
    const size_t MB = 1 << 20;
    __hip_bfloat16* qc  = (__hip_bfloat16*)(ws + 0 * MB);
    __hip_bfloat16* kc  = (__hip_bfloat16*)(ws + 4 * MB);
    __hip_bfloat16* vc  = (__hip_bfloat16*)(ws + 8 * MB);
    __hip_bfloat16* wqc = (__hip_bfloat16*)(ws + 12 * MB);
    __hip_bfloat16* wkc = (__hip_bfloat16*)(ws + 12 * MB + 512 * 1024);
    __hip_bfloat16* wvc = (__hip_bfloat16*)(ws + 13 * MB);
    __hip_bfloat16* woc = (__hip_bfloat16*)(ws + 13 * MB + 512 * 1024);
    __hip_bfloat16* qbh = (__hip_bfloat16*)(ws + 14 * MB);
    __hip_bfloat16* kbh = (__hip_bfloat16*)(ws + 18 * MB);
    __hip_bfloat16* vt  = (__hip_bfloat16*)(ws + 22 * MB);
    __hip_bfloat16* x   = (__hip_bfloat16*)(ws + 26 * MB);
    __hip_bfloat16* bS  = (__hip_bfloat16*)(ws + 32 * MB);  // 64 MB
    float*          Op  = (float*)(ws + 96 * MB);           // 16 MB
    float2*         Ml  = (float2*)(ws + 112 * MB);         // 512 KB

    hipLaunchKernelGGL(prep, dim3(7680), dim3(256), 0, stream,
                       query, key, value, Wq, Wk, Wv, Wo, dist, mask,
                       cw1, cb1, cw2, cb2,
                       qc, kc, vc, wqc, wkc, wvc, woc, bS);
    hipLaunchKernelGGL(proj_gemm, dim3(4, 32, 3), dim3(256), 0, stream,
                       qc, kc, vc, wqc, wkc, wvc, bq, bk, bv, qbh, kbh, vt);
    hipLaunchKernelGGL(attn_split, dim3(16, 32, 2), dim3(256), 0, stream,
                       qbh, kbh, vt, bS, Op, Ml);
    hipLaunchKernelGGL(combine, dim3(4096), dim3(256), 0, stream, Op, Ml, x);
    hipLaunchKernelGGL(out_gemm, dim3(8, 32), dim3(256), 0, stream,
                       x, woc, bo, out);
}